// Round 11
// baseline (405.516 us; speedup 1.0000x reference)
//
#include <hip/hip_runtime.h>
#include <hip/hip_bf16.h>

// Problem constants
#define BB 4
#define NN 4096
#define DIMM 512
#define HH 8
#define DD 64
#define MM 256
#define LL 16
#define BHH 32
#define NROW (BB*NN)      // 16384
#define KS 33

typedef __attribute__((ext_vector_type(8))) short short8;   // 8 bf16 = 4 VGPR
typedef __attribute__((ext_vector_type(4))) float float4v;  // MFMA C/D

static __device__ __forceinline__ unsigned short bf16_bits(float v) {
    __hip_bfloat16 h = __float2bfloat16(v);
    return *reinterpret_cast<unsigned short*>(&h);
}

// async global->LDS 16B per lane; lds base must be wave-uniform (lane i lands at +16*i)
static __device__ __forceinline__ void gl_lds16(const void* g, void* l) {
    __builtin_amdgcn_global_load_lds((const __attribute__((address_space(1))) void*)g,
                                     (__attribute__((address_space(3))) void*)l, 16, 0, 0);
}

// barrier that waits LDS ops only — leaves global (vmcnt) prefetch loads in
// flight across the barrier (plain __syncthreads drains vmcnt(0), exposing the
// full load latency every chunk).
static __device__ __forceinline__ void bar_nv() {
    asm volatile("s_waitcnt lgkmcnt(0)\ns_barrier" ::: "memory");
}

// XCD-chunk swizzle (T1): hardware round-robins consecutive block ids across
// the 8 XCDs; remap so each XCD executes a CONTIGUOUS logical range, making
// neighbor blocks (which share operand panels) hit the same private L2.
// Bijective iff nwg % 8 == 0 (true for every grid below).
static __device__ __forceinline__ int xcd_swz(int hw, int nwg) {
    return (hw & 7) * (nwg >> 3) + (hw >> 3);
}

// ---------------------------------------------------------------------------
// LayerNorm: one block per row of [16384, 512] -> bf16 output
__launch_bounds__(256)
__global__ void ln_kernel(const float* __restrict__ x,
                          const float* __restrict__ w,
                          const float* __restrict__ bvec,
                          __hip_bfloat16* __restrict__ xn) {
    int row = blockIdx.x;
    int t = threadIdx.x;
    const float* xr = x + (long)row * DIMM;
    float v0 = xr[t];
    float v1 = xr[t + 256];
    __shared__ float red[256];
    red[t] = v0 + v1;
    __syncthreads();
    for (int off = 128; off > 0; off >>= 1) { if (t < off) red[t] += red[t + off]; __syncthreads(); }
    float mu = red[0] * (1.0f / DIMM);
    __syncthreads();
    float d0 = v0 - mu, d1 = v1 - mu;
    red[t] = d0 * d0 + d1 * d1;
    __syncthreads();
    for (int off = 128; off > 0; off >>= 1) { if (t < off) red[t] += red[t + off]; __syncthreads(); }
    float var = red[0] * (1.0f / DIMM);
    float rs = rsqrtf(var + 1e-5f);
    xn[(long)row * DIMM + t]       = __float2bfloat16(d0 * rs * w[t]       + bvec[t]);
    xn[(long)row * DIMM + t + 256] = __float2bfloat16(d1 * rs * w[t + 256] + bvec[t + 256]);
}

// ---------------------------------------------------------------------------
// Transpose + fp32->bf16: out[N][K] = bf16(in[K][N])
__launch_bounds__(256)
__global__ void transpose_bf16(const float* __restrict__ in, __hip_bfloat16* __restrict__ outp,
                               int K, int N) {
    __shared__ float tile[32][33];
    int k0 = blockIdx.y * 32, n0 = blockIdx.x * 32;
    int tx = threadIdx.x & 31, ty = threadIdx.x >> 5;  // ty 0..7
    #pragma unroll
    for (int i = 0; i < 32; i += 8)
        tile[ty + i][tx] = in[(long)(k0 + ty + i) * N + n0 + tx];
    __syncthreads();
    #pragma unroll
    for (int i = 0; i < 32; i += 8)
        outp[(long)(n0 + ty + i) * K + k0 + tx] = __float2bfloat16(tile[tx][ty + i]);
}

// ---------------------------------------------------------------------------
// bf16 MFMA GEMM: C[M,N] = A[M,K]bf16 @ Bt[N,K]bf16^T.
// 128x128 tile, BK=64, 256 threads = 4 waves (2x2), 4x4 16x16x32 frags/wave.
// LDS 16B-chunk XOR swizzle (pre-swizzled global source + swizzled LDS read).
// Round-11: LDS DOUBLE-BUFFER with counted vmcnt (T3/T4 minimal form). Tile
// k+1's 8 global_load_lds are issued into the other buffer, then
// s_waitcnt vmcnt(8) (tile k complete, k+1 STAYS IN FLIGHT) + raw s_barrier.
// No vmcnt(0) drain in the main loop — the barrier-drain stall (the ~20%
// structural cost of __syncthreads with gl_lds) is removed.
enum { EPI_NONE = 0, EPI_QKV = 1, EPI_OUT = 2 };

template<int EPI>
__launch_bounds__(256)
__global__ void gemm_mfma(const __hip_bfloat16* __restrict__ A,
                          const __hip_bfloat16* __restrict__ Bt,
                          float* __restrict__ C, int M, int N, int K,
                          const float* __restrict__ bias,
                          const float* __restrict__ resid,
                          __hip_bfloat16* __restrict__ qb,
                          __hip_bfloat16* __restrict__ kb,
                          __hip_bfloat16* __restrict__ vtb) {
    __shared__ __hip_bfloat16 As[2][128][64];
    __shared__ __hip_bfloat16 Bs[2][128][64];
    const int t = threadIdx.x;
    const int hw = blockIdx.y * gridDim.x + blockIdx.x;
    const int lg = xcd_swz(hw, gridDim.x * gridDim.y);
    const int m0 = (lg / gridDim.x) * 128, n0 = (lg % gridDim.x) * 128;
    const int wave = t >> 6, lane = t & 63;
    const int wrow = wave >> 1, wcol = wave & 1;
    const int lm = lane & 15, quad = lane >> 4;
    const int wbase = wave * 64;   // wave's chunk base within a 256-chunk group

    // hoisted staging pointers (bumped +64 elems per K-step); LDS base is buf0,
    // buffer stride = 8192 elems (16KB).
    const __hip_bfloat16* gA[4];
    const __hip_bfloat16* gB[4];
    __hip_bfloat16* lA[4];
    __hip_bfloat16* lB[4];
    #pragma unroll
    for (int p = 0; p < 4; ++p) {
        int idx = t + p * 256;
        int r = idx >> 3;
        int csrc = ((idx & 7) ^ (r & 7)) * 8;   // swizzled source chunk
        int cb = (p * 256 + wbase) * 8;          // wave-uniform LDS element base
        gA[p] = &A[(long)(m0 + r) * K + csrc];
        gB[p] = &Bt[(long)(n0 + r) * K + csrc];
        lA[p] = &As[0][0][0] + cb;
        lB[p] = &Bs[0][0][0] + cb;
    }

    // hoisted swizzled LDS read bases (buf0): [ksi parity][fragment]
    const char* pA[2][4];
    const char* pB[2][4];
    #pragma unroll
    for (int i = 0; i < 4; ++i) {
        int ra = wrow * 64 + i * 16 + lm;
        int rb = wcol * 64 + i * 16 + lm;
        int ca = quad ^ (ra & 3), ra2 = (ra >> 2) & 1;
        int cb2 = quad ^ (rb & 3), rb2 = (rb >> 2) & 1;
        pA[0][i] = (const char*)&As[0][ra][(4 * ra2       + ca)  * 8];
        pA[1][i] = (const char*)&As[0][ra][(4 * (1 - ra2) + ca)  * 8];
        pB[0][i] = (const char*)&Bs[0][rb][(4 * rb2       + cb2) * 8];
        pB[1][i] = (const char*)&Bs[0][rb][(4 * (1 - rb2) + cb2) * 8];
    }

    float4v acc[4][4] = {};
    const int kiters = K >> 6;

    // prologue: tile 0 -> buf 0
    #pragma unroll
    for (int p = 0; p < 4; ++p) {
        gl_lds16(gA[p], lA[p]);
        gl_lds16(gB[p], lB[p]);
        gA[p] += 64;
        gB[p] += 64;
    }

    for (int k = 0; k < kiters; ++k) {
        const int cur = k & 1;
        if (k + 1 < kiters) {
            const int nxt = cur ^ 1;
            #pragma unroll
            for (int p = 0; p < 4; ++p) {
                gl_lds16(gA[p], lA[p] + nxt * 8192);
                gl_lds16(gB[p], lB[p] + nxt * 8192);
                gA[p] += 64;
                gB[p] += 64;
            }
            asm volatile("s_waitcnt vmcnt(8)" ::: "memory");  // tile k done; k+1 in flight
        } else {
            asm volatile("s_waitcnt vmcnt(0)" ::: "memory");  // last tile
        }
        __builtin_amdgcn_s_barrier();                          // collective: tile k visible

        const int bo = cur * 16384;                            // buffer byte offset
        #pragma unroll
        for (int ksu = 0; ksu < 2; ++ksu) {
            short8 af[4], bfr[4];
            #pragma unroll
            for (int i = 0; i < 4; ++i) {
                af[i]  = *(const short8*)(pA[ksu][i] + bo);
                bfr[i] = *(const short8*)(pB[ksu][i] + bo);
            }
            #pragma unroll
            for (int i = 0; i < 4; ++i)
                #pragma unroll
                for (int j = 0; j < 4; ++j)
                    acc[i][j] = __builtin_amdgcn_mfma_f32_16x16x32_bf16(af[i], bfr[j], acc[i][j], 0, 0, 0);
        }
        bar_nv();   // all reads of buf cur done before it is overwritten (iter k+2)
    }

    #pragma unroll
    for (int i = 0; i < 4; ++i) {
        #pragma unroll
        for (int j = 0; j < 4; ++j) {
            int rowb = m0 + wrow * 64 + i * 16 + quad * 4;
            int col  = n0 + wcol * 64 + j * 16 + lm;
            if (EPI == EPI_QKV) {
                int b = rowb >> 12, seq = rowb & (NN - 1);
                int which = col >> 9, rem = col & 511;
                int h = rem >> 6, dd = rem & 63;
                int bh = b * HH + h;
                if (which == 0) {
                    #pragma unroll
                    for (int r = 0; r < 4; ++r)
                        qb[((long)bh * NN + seq + r) * DD + dd] = __float2bfloat16(acc[i][j][r] * 0.125f);
                } else if (which == 1) {
                    #pragma unroll
                    for (int r = 0; r < 4; ++r)
                        kb[((long)bh * NN + seq + r) * DD + dd] = __float2bfloat16(acc[i][j][r]);
                } else {
                    union { unsigned long long u; unsigned short s[4]; } pk;
                    #pragma unroll
                    for (int r = 0; r < 4; ++r) pk.s[r] = bf16_bits(acc[i][j][r]);
                    *(unsigned long long*)&vtb[((long)bh * DD + dd) * NN + seq] = pk.u;
                }
            } else { // EPI_OUT
                #pragma unroll
                for (int r = 0; r < 4; ++r) {
                    int row = rowb + r;
                    C[(long)row * N + col] = acc[i][j][r] + bias[col] + resid[(long)row * N + col];
                }
            }
        }
    }
}

// ---------------------------------------------------------------------------
// Batched bf16 MFMA GEMM for pinv: 32 batches of 256x256x256, 64x64 tile,
// grid (4,4,32)=512 blocks. Single-phase staging (16 gl_lds, ONE barrier) then
// 64 MFMAs. XCD-chunk swizzle: all 16 tiles of a batch on one XCD.
__launch_bounds__(256)
__global__ void gemm_pinv(const __hip_bfloat16* __restrict__ A,
                          const __hip_bfloat16* __restrict__ Bt,
                          __hip_bfloat16* __restrict__ CnBf,
                          float* __restrict__ CnF,
                          __hip_bfloat16* __restrict__ CTbf,
                          float diag, float sgn, float scale) {
    __shared__ __hip_bfloat16 As[64][256];
    __shared__ __hip_bfloat16 Bs[64][256];
    const int t = threadIdx.x;
    const int hw = (blockIdx.z * 4 + blockIdx.y) * 4 + blockIdx.x;
    const int lg = xcd_swz(hw, 512);
    const long base = (long)(lg >> 4) << 16;
    const int m0 = ((lg >> 2) & 3) * 64, n0 = (lg & 3) * 64;
    const int wave = t >> 6, lane = t & 63;
    const int wr = wave >> 1, wc = wave & 1;
    const int lm = lane & 15, quad = lane >> 4;
    const __hip_bfloat16* Ab = A + base;
    const __hip_bfloat16* Bb = Bt + base;

    #pragma unroll
    for (int p = 0; p < 8; ++p) {
        int idx = t + p * 256;                 // 0..2047
        int r = idx >> 5;                      // row 0..63
        int csrc = ((idx & 31) ^ (r & 7)) * 8; // swizzled source chunk (elems)
        int cb = idx * 8;                      // linear LDS elem offset
        gl_lds16(&Ab[(long)(m0 + r) * 256 + csrc], &As[0][0] + cb);
        gl_lds16(&Bb[(long)(n0 + r) * 256 + csrc], &Bs[0][0] + cb);
    }

    // per-parity swizzled read bases; higher K-bits walk at +128B compile-time
    const char* pA[2][2];
    const char* pB[2][2];
    #pragma unroll
    for (int i = 0; i < 2; ++i) {
        int ra = wr * 32 + i * 16 + lm;
        int rb = wc * 32 + i * 16 + lm;
        int ca = quad ^ (ra & 3), ra2 = (ra >> 2) & 1;
        int cb2 = quad ^ (rb & 3), rb2 = (rb >> 2) & 1;
        pA[0][i] = (const char*)&As[ra][(4 * ra2       + ca)  * 8];
        pA[1][i] = (const char*)&As[ra][(4 * (1 - ra2) + ca)  * 8];
        pB[0][i] = (const char*)&Bs[rb][(4 * rb2       + cb2) * 8];
        pB[1][i] = (const char*)&Bs[rb][(4 * (1 - rb2) + cb2) * 8];
    }
    __syncthreads();

    float4v acc[2][2] = {};
    #pragma unroll
    for (int ksu = 0; ksu < 8; ++ksu) {
        short8 af[2], bfr[2];
        #pragma unroll
        for (int i = 0; i < 2; ++i) {
            af[i]  = *(const short8*)(pA[ksu & 1][i] + (ksu >> 1) * 128);
            bfr[i] = *(const short8*)(pB[ksu & 1][i] + (ksu >> 1) * 128);
        }
        #pragma unroll
        for (int i = 0; i < 2; ++i)
            #pragma unroll
            for (int j = 0; j < 2; ++j)
                acc[i][j] = __builtin_amdgcn_mfma_f32_16x16x32_bf16(af[i], bfr[j], acc[i][j], 0, 0, 0);
    }

    #pragma unroll
    for (int i = 0; i < 2; ++i)
        #pragma unroll
        for (int j = 0; j < 2; ++j) {
            const int rowb = wr * 32 + i * 16 + quad * 4;   // 4 consecutive rows
            const int col  = wc * 32 + j * 16 + lm;
            union { unsigned long long u; unsigned short s[4]; } pk;
            #pragma unroll
            for (int r = 0; r < 4; ++r) {
                float v = acc[i][j][r] * scale;
                long off = base + (long)(m0 + rowb + r) * 256 + n0 + col;
                if (CnBf) CnBf[off] = __float2bfloat16(v);
                if (CnF)  CnF[off]  = v;
                float tv = sgn * v + ((m0 + rowb + r) == (n0 + col) ? diag : 0.0f);
                pk.s[r] = bf16_bits(tv);
            }
            if (CTbf)
                *(unsigned long long*)&CTbf[base + (long)(n0 + col) * 256 + m0 + rowb] = pk.u;
        }
}

// ---------------------------------------------------------------------------
// pinv prep: a2_bf = bf16(a2); z0T = bf16(s*a2); z0n = bf16(s*a2^T). grid (4,4,32).
__launch_bounds__(256)
__global__ void pinv_prep(const float* __restrict__ a2, const float* __restrict__ scl,
                          __hip_bfloat16* __restrict__ a2bf, __hip_bfloat16* __restrict__ z0T,
                          __hip_bfloat16* __restrict__ z0n) {
    __shared__ float tl[64][65];
    const int t = threadIdx.x;
    const long base = (long)blockIdx.z << 16;
    const int i0 = blockIdx.y * 64, j0 = blockIdx.x * 64;
    float s = scl[0];
    #pragma unroll
    for (int p = 0; p < 16; ++p) {
        int idx = t + p * 256;
        int r = idx >> 6, c = idx & 63;
        long off = base + (long)(i0 + r) * 256 + j0 + c;
        float v = a2[off];
        a2bf[off] = __float2bfloat16(v);
        float zv = v * s;
        z0T[off] = __float2bfloat16(zv);
        tl[r][c] = zv;
    }
    __syncthreads();
    int r = t & 63;
    #pragma unroll
    for (int u = 0; u < 16; ++u) {
        int c = u * 4 + (t >> 6);
        z0n[base + (long)(j0 + c) * 256 + i0 + r] = __float2bfloat16(tl[r][c]);
    }
}

// ---------------------------------------------------------------------------
// Generic fp32 tiled GEMM (sim2 / wm). 64x64 tile, BK=16. XCD-chunk swizzled.
template<int EPI, bool TRANSB>
__launch_bounds__(256)
__global__ void gemm64(const float* __restrict__ A, const float* __restrict__ Bm,
                       float* __restrict__ C,
                       int M, int N, int K, long sA, long sB, long sC, float alpha) {
    const int gx = gridDim.x, gxy = gridDim.x * gridDim.y;
    const int hw = blockIdx.z * gxy + blockIdx.y * gx + blockIdx.x;
    const int lg = xcd_swz(hw, gxy * gridDim.z);
    const int bz = lg / gxy;
    const int rem = lg % gxy;
    const float* Ab = A + (long)bz * sA;
    const float* Bb = Bm + (long)bz * sB;
    float* Cb = C + (long)bz * sC;

    __shared__ float As[16][64];
    __shared__ float Bs[16][64];

    const int tid = threadIdx.x;
    const int tx = tid & 15;
    const int ty = tid >> 4;
    const int m0 = (rem / gx) * 64;
    const int n0 = (rem % gx) * 64;

    float acc[4][4] = {};

    for (int k0 = 0; k0 < K; k0 += 16) {
        {
            int r  = tid >> 2;
            int kk = (tid & 3) * 4;
            float4 va = *(const float4*)(Ab + (long)(m0 + r) * K + k0 + kk);
            As[kk + 0][r] = va.x; As[kk + 1][r] = va.y; As[kk + 2][r] = va.z; As[kk + 3][r] = va.w;
        }
        if (!TRANSB) {
            int kk = tid >> 4;
            int j  = (tid & 15) * 4;
            float4 vb = *(const float4*)(Bb + (long)(k0 + kk) * N + n0 + j);
            Bs[kk][j + 0] = vb.x; Bs[kk][j + 1] = vb.y; Bs[kk][j + 2] = vb.z; Bs[kk][j + 3] = vb.w;
        } else {
            int j  = tid >> 2;
            int kk = (tid & 3) * 4;
            float4 vb = *(const float4*)(Bb + (long)(n0 + j) * K + k0 + kk);
            Bs[kk + 0][j] = vb.x; Bs[kk + 1][j] = vb.y; Bs[kk + 2][j] = vb.z; Bs[kk + 3][j] = vb.w;
        }
        __syncthreads();
        #pragma unroll
        for (int kk = 0; kk < 16; ++kk) {
            float a0 = As[kk][ty * 4 + 0], a1 = As[kk][ty * 4 + 1];
            float a2 = As[kk][ty * 4 + 2], a3 = As[kk][ty * 4 + 3];
            float b0 = Bs[kk][tx * 4 + 0], b1 = Bs[kk][tx * 4 + 1];
            float b2 = Bs[kk][tx * 4 + 2], b3 = Bs[kk][tx * 4 + 3];
            acc[0][0] += a0 * b0; acc[0][1] += a0 * b1; acc[0][2] += a0 * b2; acc[0][3] += a0 * b3;
            acc[1][0] += a1 * b0; acc[1][1] += a1 * b1; acc[1][2] += a1 * b2; acc[1][3] += a1 * b3;
            acc[2][0] += a2 * b0; acc[2][1] += a2 * b1; acc[2][2] += a2 * b2; acc[2][3] += a2 * b3;
            acc[3][0] += a3 * b0; acc[3][1] += a3 * b1; acc[3][2] += a3 * b2; acc[3][3] += a3 * b3;
        }
        __syncthreads();
    }

    #pragma unroll
    for (int r = 0; r < 4; ++r)
        #pragma unroll
        for (int c = 0; c < 4; ++c)
            Cb[(long)(m0 + ty * 4 + r) * N + n0 + tx * 4 + c] = acc[r][c] * alpha;
}

// ---------------------------------------------------------------------------
// Landmark means from bf16 q/k; writes fp32 (for sim2) and bf16 (for MFMA flash).
__global__ void landmark_kernel(const __hip_bfloat16* __restrict__ qb,
                                const __hip_bfloat16* __restrict__ kb,
                                float* __restrict__ q_l, float* __restrict__ k_l,
                                __hip_bfloat16* __restrict__ q_lb,
                                __hip_bfloat16* __restrict__ k_lb) {
    int bh = blockIdx.x >> 8;
    int m  = blockIdx.x & 255;
    int d  = threadIdx.x;     // 64
    const __hip_bfloat16* src = (blockIdx.y ? kb : qb) + ((long)bh * NN + m * LL) * DD + d;
    float s = 0.f;
    #pragma unroll
    for (int t = 0; t < LL; ++t) s += __bfloat162float(src[(long)t * DD]);
    s *= (1.0f / LL);
    long off = ((long)bh * MM + m) * DD + d;
    if (blockIdx.y) { k_l[off] = s; k_lb[off] = __float2bfloat16(s); }
    else            { q_l[off] = s; q_lb[off] = __float2bfloat16(s); }
}

// ---------------------------------------------------------------------------
__launch_bounds__(256)
__global__ void softmax256_kernel(float* __restrict__ a) {
    long row = blockIdx.x;
    int t = threadIdx.x;
    float* r = a + row * 256;
    float v = r[t];
    __shared__ float red[256];
    red[t] = v;
    __syncthreads();
    for (int off = 128; off > 0; off >>= 1) { if (t < off) red[t] = fmaxf(red[t], red[t + off]); __syncthreads(); }
    float mx = red[0];
    __syncthreads();
    float e = __expf(v - mx);
    red[t] = e;
    __syncthreads();
    for (int off = 128; off > 0; off >>= 1) { if (t < off) red[t] += red[t + off]; __syncthreads(); }
    r[t] = e / red[0];
}

// ---------------------------------------------------------------------------
// Max column-sum of a2 (row-sums are 1.0: softmax rows). 256 blocks.
__launch_bounds__(256)
__global__ void redmax_kernel(const float* __restrict__ a2, float* __restrict__ red) {
    int blk = blockIdx.x;            // bh*8 + cg
    int bh = blk >> 3, cg = blk & 7;
    int t = threadIdx.x;
    const float* Ab = a2 + ((long)bh << 16) + cg * 32;
    int c = t & 31, rg = t >> 5;     // col 0..31, row-group 0..7
    float s = 0.f;
    for (int r = rg * 32; r < rg * 32 + 32; ++r) s += Ab[(long)r * 256 + c];
    __shared__ float m[256];
    m[t] = s;
    __syncthreads();
    if (t < 32) {
        float cs = 0.f;
        #pragma unroll
        for (int g = 0; g < 8; ++g) cs += m[t + 32 * g];
        m[t] = cs;
    }
    __syncthreads();
    if (t == 0) {
        float mx = m[0];
        #pragma unroll
        for (int i = 1; i < 32; ++i) mx = fmaxf(mx, m[i]);
        red[blk] = mx;
    }
}

__launch_bounds__(256)
__global__ void scale_kernel(const float* __restrict__ red, float* __restrict__ scl) {
    __shared__ float b[256];
    int t = threadIdx.x;  // 256
    b[t] = red[t];
    __syncthreads();
    for (int off = 128; off > 0; off >>= 1) {
        if (t < off) b[t] = fmaxf(b[t], b[t + off]);
        __syncthreads();
    }
    if (t == 0) scl[0] = 1.0f / b[0];
}

// ---------------------------------------------------------------------------
// a3v flash MFMA: block = 64 landmark rows x 1024-seq slice (16 chunks of 64).
// K/V register prefetch one chunk ahead + lgkm-only barriers. XCD-swizzled:
// all 16 blocks of one bh (sharing K/V) land on the same XCD.
__launch_bounds__(256)
__global__ void a3v_mfma(const __hip_bfloat16* __restrict__ qlb,
                         const __hip_bfloat16* __restrict__ kb,
                         const __hip_bfloat16* __restrict__ vtb,
                         float* __restrict__ opart, float* __restrict__ lpart) {
    const int hw = blockIdx.y * 16 + blockIdx.x;
    const int lg = xcd_swz(hw, 512);
    const int bh = lg >> 4;
    const int mt = (lg >> 2) & 3;
    const int ns = lg & 3;
    const int t = threadIdx.x;
    const int wave = t >> 6, lane = t & 63;
    const int wr = wave >> 1, wc = wave & 1;
    const int lm = lane & 15, quad = lane >> 4;
    const int r8 = t >> 3, c8 = (t & 7) * 8;

    __shared__ __hip_bfloat16 Qs[64][72];
    __shared__ __hip_bfloat16 Ks[64][72];
    __shared__ __hip_bfloat16 Vt[64][72];
    __shared__ __hip_bfloat16 Ps[64][72];
    __shared__ float lredS[64][2];

    {
        const __hip_bfloat16* qbase = qlb + ((long)bh * MM + mt * 64) * DD;
        *(uint4*)&Qs[r8][c8]      = *(const uint4*)&qbase[(long)r8 * DD + c8];
        *(uint4*)&Qs[r8 + 32][c8] = *(const uint4*)&qbase[(long)(r8 + 32) * DD + c8];
    }

    float4v acc[2][2] = {};
    float lacc[2][4] = {};
    const __hip_bfloat16* kbase = kb + ((long)bh * NN + ns * 1024) * DD;
    const __hip_bfloat16* vbase = vtb + (long)bh * DD * NN + ns * 1024;

    // prefetch chunk 0 into regs
    uint4 kv0 = *(const uint4*)&kbase[(long)r8 * DD + c8];
    uint4 kv1 = *(const uint4*)&kbase[(long)(r8 + 32) * DD + c8];
    uint4 vv0 = *(const uint4*)&vbase[(long)r8 * NN + c8];
    uint4 vv1 = *(const uint4*)&vbase[(long)(r8 + 32) * NN + c8];
    bar_nv();   // Qs visible; prefetch stays in flight

    for (int ch = 0; ch < 16; ++ch) {
        *(uint4*)&Ks[r8][c8]      = kv0;
        *(uint4*)&Ks[r8 + 32][c8] = kv1;
        *(uint4*)&Vt[r8][c8]      = vv0;
        *(uint4*)&Vt[r8 + 32][c8] = vv1;
        if (ch < 15) {   // issue next chunk's loads; they fly during compute
            kv0 = *(const uint4*)&kbase[(long)((ch + 1) * 64 + r8) * DD + c8];
            kv1 = *(const uint4*)&kbase[(long)((ch + 1) * 64 + r8 + 32) * DD + c8];
            vv0 = *(const uint4*)&vbase[(long)r8 * NN + (ch + 1) * 64 + c8];
            vv1 = *(const uint4*)&vbase[(long)(r8 + 32) * NN + (ch + 1) * 64 + c8];
        }
        bar_nv();

        float4v s[2][2] = {};
        #pragma unroll
        for (int ks = 0; ks < 64; ks += 32) {
            short8 af[2], bfr[2];
            #pragma unroll
            for (int i = 0; i < 2; ++i) {
                af[i]  = *(const short8*)&Qs[wr * 32 + i * 16 + lm][ks + quad * 8];
                bfr[i] = *(const short8*)&Ks[wc * 32 + i * 16 + lm][ks + quad * 8];
            }
            #pragma unroll
            for (int i = 0; i < 2; ++i)
                #pragma unroll
                for (int j = 0; j < 2; ++j)
                    s[i][j] = __builtin_amdgcn_mfma_f32_16x16x32_bf16(af[i], bfr[j], s[i][j], 0, 0, 0);
        }
        #pragma unroll
        for (int i = 0; i < 2; ++i)
            #pragma unroll
            for (int j = 0; j < 2; ++j)
                #pragma unroll
                for (int r2 = 0; r2 < 4; ++r2) {
                    float e = __expf(s[i][j][r2]);
                    lacc[i][r2] += e;
                    Ps[wr * 32 + i * 16 + quad * 4 + r2][wc * 32 + j * 16 + lm] = __float2bfloat16(e);
                }
        bar_nv();

        #pragma unroll
        for (int ks = 0; ks < 64; ks += 32) {
            short8 af[2], bfr[2];
            #pragma unroll
            for (int i = 0; i < 2; ++i) {
                af[i]  = *(const short8*)&Ps[wr * 32 + i * 16 + lm][ks + quad * 8];
                bfr[i] = *(const short8*)&Vt[wc * 32 + i * 16 + lm][ks + quad * 8];
            }
            #pragma unroll
            for (int i = 0; i < 2; ++i)
                #pragma unroll
                for (int j = 0; j < 2; ++j)
                    acc[i][j] = __builtin_amdgcn_mfma_f32_16x16x32_bf16(af[i], bfr[j], acc[i][j], 0, 0, 0);
        }
        bar_nv();
    }

    // wave-level l-sum reduction over the 16 lm lanes
    #pragma unroll
    for (int i = 0; i < 2; ++i)
        #pragma unroll
        for (int r2 = 0; r2 < 4; ++r2) {
            float s = lacc[i][r2];
            s += __shfl_xor(s, 1);
            s += __shfl_xor(s, 2);
            s += __shfl_xor(s, 4);
            s += __shfl_xor(s, 8);
            if (lm == 0) lredS[wr * 32 + i * 16 + quad * 4 + r2][wc] = s;
        }
    __syncthreads();
    if (t < 64)
        lpart[((bh * 4 + mt) * 4 + ns) * 64 + t] = lredS[t][0] + lredS[t][1];
    const long pbase = ((long)((bh * 4 + mt) * 4 + ns)) << 12;
    #pragma unroll
    for (int i = 0; i < 2; ++i)
        #pragma unroll
        for (int j = 0; j < 2; ++j)
            #pragma unroll
            for (int r2 = 0; r2 < 4; ++r2)
                opart[pbase + (long)(wr * 32 + i * 16 + quad * 4 + r2) * 64 + wc * 32 + j * 16 + lm] = acc[i][j][r2];
}

// stage 2: combine 4 n-split partials
__global__ void a3v_combine(const float* __restrict__ opart, const float* __restrict__ lpart,
                            float* __restrict__ a3v) {
    int idx = blockIdx.x * 256 + threadIdx.x;
    int d  = idx & 63;
    int m  = (idx >> 6) & 255;
    int bh = idx >> 14;
    int mt = m >> 6, r = m & 63;
    int pb = (bh * 4 + mt) * 4;
    float osum = 0.f, lsum = 0.f;
    #pragma unroll
    for (int ns = 0; ns < 4; ++ns) {
        osum += opart[(((long)(pb + ns)) << 12) + r * 64 + d];
        lsum += lpart[(pb + ns) * 64 + r];
    }
    a3v[((long)bh * MM + m) * DD + d] = osum / lsum;
}

// ---------------------------------------------------------------------------
// wm transpose -> bf16: wtb[bh][dd][m] = bf16(wm[bh][m][dd]). One block per bh.
__launch_bounds__(256)
__global__ void wmT_kernel(const float* __restrict__ wm, __hip_bfloat16* __restrict__ wtb) {
    __shared__ float tile[64][65];
    const int bh = blockIdx.x;
    const int t = threadIdx.x;
    for (int mc = 0; mc < 4; ++mc) {
        #pragma unroll
        for (int p = 0; p < 16; ++p) {
            int idx = t + p * 256;
            int r = idx >> 6, c = idx & 63;
            tile[r][c] = wm[((long)bh * MM + mc * 64 + r) * DD + c];
        }
        __syncthreads();
        #pragma unroll
        for (int p = 0; p < 16; ++p) {
            int idx = t + p * 256;
            int dd = idx >> 6, m = idx & 63;
            wtb[((long)bh * DD + dd) * MM + mc * 64 + m] = __float2bfloat16(tile[m][dd]);
        }
        __syncthreads();
    }
}

// ---------------------------------------------------------------------------
// attn_out flash MFMA + Toeplitz-MFMA depthwise conv.
// Conv computed up front; Tpl aliases the Ks/Wt LDS; K/W register prefetch one
// chunk ahead + lgkm-only barriers. XCD-swizzled: 64 blocks of one bh (sharing
// klb/wtb) land on the same XCD.
__launch_bounds__(256)
__global__ void attn_out_mfma(const __hip_bfloat16* __restrict__ qb,
                              const __hip_bfloat16* __restrict__ klb,
                              const __hip_bfloat16* __restrict__ wtb,
                              const __hip_bfloat16* __restrict__ vtb,
                              const float* __restrict__ convw,
                              __hip_bfloat16* __restrict__ ctx) {
    const int hw = blockIdx.y * 64 + blockIdx.x;
    const int lg = xcd_swz(hw, 2048);
    const int bh = lg >> 6;
    const int b = bh >> 3, h = bh & 7;
    const int i0 = (lg & 63) * 64;
    const int t = threadIdx.x;
    const int wave = t >> 6, lane = t & 63;
    const int wr = wave >> 1, wc = wave & 1;
    const int lm = lane & 15, quad = lane >> 4;
    const int r8 = t >> 3, c8 = (t & 7) * 8;

    __shared__ __hip_bfloat16 Qs[64][72];
    __shared__ __hip_bfloat16 KW[2][64][72];   // Ks = KW[0], Wt = KW[1]; Tpl aliases
    __shared__ __hip_bfloat16 Ps[64][72];
    __shared__ __hip_bfloat16 Vc[64][104];     // v window [i0-16, i0+80): cols 0..95
    __shared__ float lredS[64][2];
    __shared__ float dsum[64];
    __shared__ float cwS[KS];
    __hip_bfloat16 (*Tpl)[104] = reinterpret_cast<__hip_bfloat16 (*)[104]>(&KW[0][0][0]);

    if (t < KS) cwS[t] = convw[h * KS + t];

    {   // stage Q tile
        const __hip_bfloat16* qbase = qb + ((long)bh * NN + i0) * DD;
        *(uint4*)&Qs[r8][c8]      = *(const uint4*)&qbase[(long)r8 * DD + c8];
        *(uint4*)&Qs[r8 + 32][c8] = *(const uint4*)&qbase[(long)(r8 + 32) * DD + c8];
    }
    {   // stage V conv window: 64 dd x 12 chunks of 8 bf16
        for (int c = t; c < 768; c += 256) {
            int dd = c / 12, u = c - dd * 12;
            int g0 = i0 - 16 + u * 8;
            const __hip_bfloat16* vrow = vtb + ((long)bh * DD + dd) * NN;
            __align__(16) __hip_bfloat16 tmp[8];
            if (g0 >= 0 && g0 + 8 <= NN) {
                *(uint4*)tmp = *(const uint4*)&vrow[g0];
            } else {
                #pragma unroll
                for (int e = 0; e < 8; ++e) {
                    int g = g0 + e;
                    tmp[e] = (g >= 0 && g < NN) ? vrow[g] : __float2bfloat16(0.f);
                }
            }
            *(uint4*)&Vc[dd][u * 8] = *(uint4*)tmp;
        }
    }
    __syncthreads();   // cwS, Qs, Vc visible

    {   // build Toeplitz matrix in the Ks/Wt space: T[r][c] = w[c-r], 0 <= c-r < 33
        int r  = t >> 2;            // 0..63
        int c0 = (t & 3) * 24;      // 4 col-groups of 24
        #pragma unroll
        for (int u = 0; u < 12; ++u) {
            int c = c0 + u * 2;
            int d0 = c - r, d1 = c + 1 - r;
            unsigned short lo = (d0 >= 0 && d0 < KS) ? bf16_bits(cwS[d0]) : (unsigned short)0;
            unsigned short hi = (d1 >= 0 && d1 < KS) ? bf16_bits(cwS[d1]) : (unsigned short)0;
            *(unsigned*)&Tpl[r][c] = ((unsigned)hi << 16) | lo;
        }
    }
    bar_nv();          // Tpl visible

    // prefetch chunk 0's K/W into regs: latency hides under the conv MFMAs
    const __hip_bfloat16* klbase = klb + (long)bh * MM * DD;
    const __hip_bfloat16* wbase  = wtb + (long)bh * DD * MM;
    uint4 kv0 = *(const uint4*)&klbase[(long)r8 * DD + c8];
    uint4 kv1 = *(const uint4*)&klbase[(long)(r8 + 32) * DD + c8];
    uint4 wv0 = *(const uint4*)&wbase[(long)r8 * MM + c8];
    uint4 wv1 = *(const uint4*)&wbase[(long)(r8 + 32) * MM + c8];

    // conv via Toeplitz MFMA: accC[row][dd] = sum_s T[row][s] * Vc[dd][s]
    float4v accC[2][2] = {};
    #pragma unroll
    for (int ks = 0; ks < 96; ks += 32) {
        short8 af[2], bfr[2];
        #pragma unroll
        for (int i = 0; i < 2; ++i) {
            af[i]  = *(const short8*)&Tpl[wr * 32 + i * 16 + lm][ks + quad * 8];
            bfr[i] = *(const short8*)&Vc[wc * 32 + i * 16 + lm][ks + quad * 8];
        }
        #pragma unroll
        for (int i = 0; i < 2; ++i)
            #pragma unroll
            for (int j = 0; j < 2; ++j)
                accC[i][j] = __builtin_amdgcn_mfma_f32_16x16x32_bf16(af[i], bfr[j], accC[i][j], 0, 0, 0);
    }
    bar_nv();          // conv reads done; KW space free for K/W staging

    float4v acc[2][2] = {};
    float lacc[2][4] = {};

    for (int ch = 0; ch < 4; ++ch) {
        *(uint4*)&KW[0][r8][c8]      = kv0;
        *(uint4*)&KW[0][r8 + 32][c8] = kv1;
        *(uint4*)&KW[1][r8][c8]      = wv0;
        *(uint4*)&KW[1][r8 + 32][c8] = wv1;
        if (ch < 3) {   // next chunk's loads fly during this chunk's compute
            kv0 = *(const uint4*)&klbase[(long)((ch + 1) * 64 + r8) * DD + c8];
            kv1 = *(const uint4*)&klbase[(long)((ch + 1) * 64 + r8 + 32) * DD + c8];
            wv0 = *(const uint4*)&wbase[(long)r8 * MM + (ch + 1) * 64 + c8];
            wv1 = *(const uint4*)&wbase[(long)(r8 + 32) * MM + (ch + 1) * 64 + c8];
        }
        bar_nv();

        float4v s[2][2] = {};
        #pragma unroll
        for (int ks = 0; ks < 64; ks += 32) {
            short8 af[2], bfr[2];
            #pragma unroll
            for (int i = 0; i < 2; ++i) {
                af[i]  = *(const short8*)&Qs[wr * 32 + i * 16 + lm][ks + quad * 8];
                bfr[i] = *(const short8*)&KW[0][wc * 32 + i * 16 + lm][ks + quad * 8];
            }
            #pragma unroll
            for (int i = 0; i < 2; ++i)
                #pragma unroll
                for (int j = 0; j < 2; ++j)
                    s[i][j] = __builtin_amdgcn_mfma_f32_16x16x32_bf16(af[i], bfr[j], s[i][j], 0, 0, 0);
        }
        #pragma unroll
        for (int i = 0; i < 2; ++i)
            #pragma unroll
            for (int j = 0; j < 2; ++j)
                #pragma unroll
                for (int r2 = 0; r2 < 4; ++r2) {
                    float e = __expf(s[i][j][r2]);
                    lacc[i][r2] += e;
                    Ps[wr * 32 + i * 16 + quad * 4 + r2][wc * 32 + j * 16 + lm] = __float2bfloat16(e);
                }
        bar_nv();

        #pragma unroll
        for (int ks = 0; ks < 64; ks += 32) {
            short8 af[2], bfr[2];
            #pragma unroll
            for (int i = 0; i < 2; ++i) {
                af[i]  = *(const short8*)&Ps[wr * 32 + i * 16 + lm][ks + quad * 8];
                bfr[i] = *(const short8*)&KW[1][wc * 32 + i * 16 + lm][ks + quad * 8];
            }
            #pragma unroll
            for (int i = 0; i < 2; ++i)
                #pragma unroll
                for (int j = 0; j < 2; ++j)
                    acc[i][j] = __builtin_amdgcn_mfma_f32_16x16x32_bf16(af[i], bfr[j], acc[i][j], 0, 0, 0);
        }
        bar_nv();
    }

    // wave-level l-sum reduction over the 16 lm lanes
    #pragma unroll
    for (int i = 0; i < 2; ++i)
        #pragma unroll
        for (int r2 = 0; r2 < 4; ++r2) {
            float s = lacc[i][r2];
            s += __shfl_xor(s, 1);
            s += __shfl_xor(s, 2);
            s += __shfl_xor(s, 4);
            s += __shfl_xor(s, 8);
            if (lm == 0) lredS[wr * 32 + i * 16 + quad * 4 + r2][wc] = s;
        }
    __syncthreads();
    if (t < 64) dsum[t] = 1.0f / (lredS[t][0] + lredS[t][1]);
    __syncthreads();

    // epilogue: normalize + add conv + single ctx write
    #pragma unroll
    for (int j = 0; j < 2; ++j) {
        int dd = wc * 32 + j * 16 + lm;
        #pragma unroll
        for (int i = 0; i < 2; ++i) {
            int R = wr * 32 + i * 16 + quad * 4;
            #pragma unroll
            for (int r2 = 0; r2 < 4; ++r2) {
                int row = R + r2;
                ctx[((long)b * NN + i0 + row) * DIMM + h * DD + dd] =
                    __float2bfloat16(acc[i][j][r2] * dsum[row] + accC[i][j][r2]);
            }
        }
    }
}

// ---------------------------------------------------------------------------
extern "C" void kernel_launch(void* const* d_in, const int* in_sizes, int n_in,
                              void* d_out, int out_size, void* d_ws, size_t ws_size,
                              hipStream_t stream) {
    const float* x      = (const float*)d_in[0];
    const float* norm_w = (const float*)d_in[1];
    const float* norm_b = (const float*)d_in[2];
    const float* Wqkv   = (const float*)d_in[3];
    const float* Wout   = (const float*)d_in[4];
    const float* bout   = (const float*)d_in[5];
    const float* conv_w = (const float*)d_in[6];
    float* out = (float*)d_out;

    float* ws = (float*)d_ws;
    size_t o = 0;
    auto alloc = [&](size_t n) { float* p = ws + o; o += n; return p; };
    auto allocb = [&](size_t n) { return (__hip_bfloat16*)alloc((n + 1) / 2); };

    __hip_bfloat16* xn_bf  = allocb((size_t)NROW * DIMM);
    __hip_bfloat16* wqt_bf = allocb((size_t)3 * DIMM * DIMM);
    __hip_bfloat16* wot_bf = allocb((size_t)DIMM * DIMM);
    __hip_bfloat16* ctx_bf = allocb((size_t)NROW * DIMM);
    __hip_bfloat16* q_bf   = allocb((size_t)BHH * NN * DD);
    __hip_bfloat16* k_bf   = allocb((size_t)BHH * NN * DD);
    __hip_bfloat16* vt_bf  = allocb((size_t)BHH * DD * NN);
    __hip_bfloat16* qlb    = allocb((size_t)BHH * MM * DD);
    __hip_bfloat16* klb    = allocb((size_t)BHH * MM * DD);
    __hip_bfloat16* wt_bf  = allocb((size_t)BHH * DD * MM);
    float* q_l  = alloc((size_t)BHH * MM * DD);
    float* k_l  = alloc((size_t)BHH * MM * DD);
    float* a2   = alloc((size_t)BHH * MM * MM);
    float* zb   = alloc((size_t)BHH * MM * MM);
    float* az   = alloc((size_t)BHH * MM * MM);
    float* gb   = alloc((size_t)BHH * MM * MM);
    float* tb   = alloc((size_t)BHH * MM * MM);
    float* z2   = alloc((size_t)BHH * MM * MM);
    float* a3v  = alloc((size_t)BHH * MM * DD);
    float* wm   = alloc((size_t)BHH * MM * DD);
    float* opart = alloc((size_t)BHH * 4 * 4 * 64 * 64);
    float* lpart = alloc((size_t)BHH * 4 * 4 * 64);
    float* red  = alloc(256);
    float* scl  = alloc(64);

    // bf16 pinv buffers aliased onto fp32 buffers dead during the bf16 phase.
    const size_t HB = 1048576;
    __hip_bfloat16* a2bf = (__hip_bfloat16*)az;
    __hip_bfloat16* znA  = (__hip_bfloat16*)(az + HB);
    __hip_bfloat16* znB  = (__hip_bfloat16*)gb;
    __hip_bfloat16* zTA  = (__hip_bfloat16*)(gb + HB);
    __hip_bfloat16* zTB  = (__hip_bfloat16*)tb;
    __hip_bfloat16* azbf = (__hip_bfloat16*)(tb + HB);
    __hip_bfloat16* g1T  = (__hip_bfloat16*)z2;
    __hip_bfloat16* g2T  = (__hip_bfloat16*)(z2 + HB);
    __hip_bfloat16* g3T  = (__hip_bfloat16*)opart;   // dead until a3v

    // 1. LayerNorm -> bf16
    ln_kernel<<<NROW, 256, 0, stream>>>(x, norm_w, norm_b, xn_bf);

    // 1b. transpose+convert weights
    transpose_bf16<<<dim3(3 * DIMM / 32, DIMM / 32), 256, 0, stream>>>(Wqkv, wqt_bf, DIMM, 3 * DIMM);
    transpose_bf16<<<dim3(DIMM / 32, DIMM / 32), 256, 0, stream>>>(Wout, wot_bf, DIMM, DIMM);

    // 2. QKV GEMM (MFMA): q,k bf16 natural; v transposed bf16
    gemm_mfma<EPI_QKV><<<dim3(3 * DIMM / 128, NROW / 128), 256, 0, stream>>>(
        xn_bf, wqt_bf, nullptr, NROW, 3 * DIMM, DIMM,
        nullptr, nullptr, q_bf, k_bf, vt_bf);

    // 3. Landmarks (fp32 + bf16)
    landmark_kernel<<<dim3(BHH * MM, 2), 64, 0, stream>>>(q_bf, k_bf, q_l, k_l, qlb, klb);

    // 4. sim2 = q_l @ k_l^T (fp32)
    gemm64<EPI_NONE, true><<<dim3(4, 4, BHH), 256, 0, stream>>>(
        q_l, k_l, a2, MM, MM, DD, (long)MM * DD, (long)MM * DD, (long)MM * MM, 1.0f);

    // 5. softmax rows -> a2
    softmax256_kernel<<<BHH * MM, 256, 0, stream>>>(a2);

    // 6-7. pinv normalization scalar (max col-sum; row-sums are 1)
    redmax_kernel<<<BHH * 8, 256, 0, stream>>>(a2, red);
    scale_kernel<<<1, 256, 0, stream>>>(red, scl);

    // 8. pinv prep
    dim3 g512(4, 4, BHH);
    pinv_prep<<<g512, 256, 0, stream>>>(a2, scl, a2bf, zTA, znA);

    // 9. Newton-Schulz: all 6 iterations bf16 MFMA; final gemm emits fp32 zb
    __hip_bfloat16 *zn = znA, *zT = zTA, *zn2 = znB, *zT2 = zTB;
    for (int it = 0; it < 6; ++it) {
        gemm_pinv<<<g512, 256, 0, stream>>>(a2bf, zT, azbf, nullptr, g1T, 7.0f, -1.0f, 1.0f);
        gemm_pinv<<<g512, 256, 0, stream>>>(azbf, g1T, nullptr, nullptr, g2T, 15.0f, -1.0f, 1.0f);
        gemm_pinv<<<g512, 256, 0, stream>>>(azbf, g2T, nullptr, nullptr, g3T, 13.0f, -1.0f, 1.0f);
        gemm_pinv<<<g512, 256, 0, stream>>>(zn, g3T, zn2, (it == 5) ? zb : nullptr, zT2,
                                            0.0f, 1.0f, 0.25f);
        __hip_bfloat16* tmp;
        tmp = zn; zn = zn2; zn2 = tmp;
        tmp = zT; zT = zT2; zT2 = tmp;
    }
    // zb = a2_inv (fp32)

    // 10. a3v = softmax(q_l . k^T) @ v   (MFMA flash)
    a3v_mfma<<<dim3(16, BHH), 256, 0, stream>>>(qlb, k_bf, vt_bf, opart, lpart);
    a3v_combine<<<BHH * MM * DD / 256, 256, 0, stream>>>(opart, lpart, a3v);

    // 11. wm = a2_inv @ a3v (fp32), then transpose -> bf16
    gemm64<EPI_NONE, false><<<dim3(1, 4, BHH), 256, 0, stream>>>(
        zb, a3v, wm, MM, DD, MM, (long)MM * MM, (long)MM * DD, (long)MM * DD, 1.0f);
    wmT_kernel<<<BHH, 256, 0, stream>>>(wm, wt_bf);

    // 12. attention out + fused depthwise conv -> bf16 ctx
    attn_out_mfma<<<dim3(NN / 64, BHH), 256, 0, stream>>>(
        q_bf, klb, wt_bf, vt_bf, conv_w, ctx_bf);

    // 13. final: out = x + ctx @ Wout + bout  (MFMA)
    gemm_mfma<EPI_OUT><<<dim3(DIMM / 128, NROW / 128), 256, 0, stream>>>(
        ctx_bf, wot_bf, out, NROW, DIMM, DIMM,
        bout, x, nullptr, nullptr, nullptr);
}

// Round 12
// 390.387 us; speedup vs baseline: 1.0388x; 1.0388x over previous
//
#include <hip/hip_runtime.h>
#include <hip/hip_bf16.h>

// Problem constants
#define BB 4
#define NN 4096
#define DIMM 512
#define HH 8
#define DD 64
#define MM 256
#define LL 16
#define BHH 32
#define NROW (BB*NN)      // 16384
#define KS 33

typedef __attribute__((ext_vector_type(8))) short short8;   // 8 bf16 = 4 VGPR
typedef __attribute__((ext_vector_type(4))) float float4v;  // MFMA C/D

static __device__ __forceinline__ unsigned short bf16_bits(float v) {
    __hip_bfloat16 h = __float2bfloat16(v);
    return *reinterpret_cast<unsigned short*>(&h);
}

// async global->LDS 16B per lane; lds base must be wave-uniform (lane i lands at +16*i)
static __device__ __forceinline__ void gl_lds16(const void* g, void* l) {
    __builtin_amdgcn_global_load_lds((const __attribute__((address_space(1))) void*)g,
                                     (__attribute__((address_space(3))) void*)l, 16, 0, 0);
}

// barrier that waits LDS ops only — leaves global (vmcnt) prefetch loads in
// flight across the barrier.
static __device__ __forceinline__ void bar_nv() {
    asm volatile("s_waitcnt lgkmcnt(0)\ns_barrier" ::: "memory");
}

// XCD-chunk swizzle (T1): remap so each XCD executes a CONTIGUOUS logical
// range. Bijective iff nwg % 8 == 0 (true for every grid below).
static __device__ __forceinline__ int xcd_swz(int hw, int nwg) {
    return (hw & 7) * (nwg >> 3) + (hw >> 3);
}

// ---------------------------------------------------------------------------
// LayerNorm: one block per row of [16384, 512] -> bf16 output
__launch_bounds__(256)
__global__ void ln_kernel(const float* __restrict__ x,
                          const float* __restrict__ w,
                          const float* __restrict__ bvec,
                          __hip_bfloat16* __restrict__ xn) {
    int row = blockIdx.x;
    int t = threadIdx.x;
    const float* xr = x + (long)row * DIMM;
    float v0 = xr[t];
    float v1 = xr[t + 256];
    __shared__ float red[256];
    red[t] = v0 + v1;
    __syncthreads();
    for (int off = 128; off > 0; off >>= 1) { if (t < off) red[t] += red[t + off]; __syncthreads(); }
    float mu = red[0] * (1.0f / DIMM);
    __syncthreads();
    float d0 = v0 - mu, d1 = v1 - mu;
    red[t] = d0 * d0 + d1 * d1;
    __syncthreads();
    for (int off = 128; off > 0; off >>= 1) { if (t < off) red[t] += red[t + off]; __syncthreads(); }
    float var = red[0] * (1.0f / DIMM);
    float rs = rsqrtf(var + 1e-5f);
    xn[(long)row * DIMM + t]       = __float2bfloat16(d0 * rs * w[t]       + bvec[t]);
    xn[(long)row * DIMM + t + 256] = __float2bfloat16(d1 * rs * w[t + 256] + bvec[t + 256]);
}

// ---------------------------------------------------------------------------
// Transpose + fp32->bf16: out[N][K] = bf16(in[K][N])
__launch_bounds__(256)
__global__ void transpose_bf16(const float* __restrict__ in, __hip_bfloat16* __restrict__ outp,
                               int K, int N) {
    __shared__ float tile[32][33];
    int k0 = blockIdx.y * 32, n0 = blockIdx.x * 32;
    int tx = threadIdx.x & 31, ty = threadIdx.x >> 5;  // ty 0..7
    #pragma unroll
    for (int i = 0; i < 32; i += 8)
        tile[ty + i][tx] = in[(long)(k0 + ty + i) * N + n0 + tx];
    __syncthreads();
    #pragma unroll
    for (int i = 0; i < 32; i += 8)
        outp[(long)(n0 + ty + i) * K + k0 + tx] = __float2bfloat16(tile[tx][ty + i]);
}

// ---------------------------------------------------------------------------
// bf16 MFMA GEMM: C[M,N] = A[M,K]bf16 @ Bt[N,K]bf16^T.
// 128x128 tile, BK=64, 4 waves (2x2), 4x4 16x16x32 frags/wave. 16B-chunk XOR
// swizzle; XCD-chunk block swizzle. Round-12: reverted to single-buffer
// (round-10 best) — explicit dbuf traded occupancy for pipeline, net zero.
enum { EPI_NONE = 0, EPI_QKV = 1, EPI_OUT = 2 };

template<int EPI>
__launch_bounds__(256)
__global__ void gemm_mfma(const __hip_bfloat16* __restrict__ A,
                          const __hip_bfloat16* __restrict__ Bt,
                          float* __restrict__ C, int M, int N, int K,
                          const float* __restrict__ bias,
                          const float* __restrict__ resid,
                          __hip_bfloat16* __restrict__ qb,
                          __hip_bfloat16* __restrict__ kb,
                          __hip_bfloat16* __restrict__ vtb) {
    __shared__ __hip_bfloat16 As[128][64];
    __shared__ __hip_bfloat16 Bs[128][64];
    const int t = threadIdx.x;
    const int hw = blockIdx.y * gridDim.x + blockIdx.x;
    const int lg = xcd_swz(hw, gridDim.x * gridDim.y);
    const int m0 = (lg / gridDim.x) * 128, n0 = (lg % gridDim.x) * 128;
    const int wave = t >> 6, lane = t & 63;
    const int wrow = wave >> 1, wcol = wave & 1;
    const int lm = lane & 15, quad = lane >> 4;
    const int wbase = wave * 64;   // wave's chunk base within a 256-chunk group

    // hoisted staging pointers (bumped +64 elems per K-step)
    const __hip_bfloat16* gA[4];
    const __hip_bfloat16* gB[4];
    __hip_bfloat16* lA[4];
    __hip_bfloat16* lB[4];
    #pragma unroll
    for (int p = 0; p < 4; ++p) {
        int idx = t + p * 256;
        int r = idx >> 3;
        int csrc = ((idx & 7) ^ (r & 7)) * 8;   // swizzled source chunk
        int cb = (p * 256 + wbase) * 8;          // wave-uniform LDS element base
        gA[p] = &A[(long)(m0 + r) * K + csrc];
        gB[p] = &Bt[(long)(n0 + r) * K + csrc];
        lA[p] = &As[0][0] + cb;
        lB[p] = &Bs[0][0] + cb;
    }

    // hoisted swizzled LDS read bases: [ksi parity][fragment]
    const __hip_bfloat16* pA[2][4];
    const __hip_bfloat16* pB[2][4];
    #pragma unroll
    for (int i = 0; i < 4; ++i) {
        int ra = wrow * 64 + i * 16 + lm;
        int rb = wcol * 64 + i * 16 + lm;
        int ca = quad ^ (ra & 3), ra2 = (ra >> 2) & 1;
        int cb2 = quad ^ (rb & 3), rb2 = (rb >> 2) & 1;
        pA[0][i] = &As[ra][(4 * ra2       + ca)  * 8];
        pA[1][i] = &As[ra][(4 * (1 - ra2) + ca)  * 8];
        pB[0][i] = &Bs[rb][(4 * rb2       + cb2) * 8];
        pB[1][i] = &Bs[rb][(4 * (1 - rb2) + cb2) * 8];
    }

    float4v acc[4][4] = {};

    for (int k0 = 0; k0 < K; k0 += 64) {
        #pragma unroll
        for (int p = 0; p < 4; ++p) {
            gl_lds16(gA[p], lA[p]);
            gl_lds16(gB[p], lB[p]);
            gA[p] += 64;
            gB[p] += 64;
        }
        __syncthreads();
        #pragma unroll
        for (int ksu = 0; ksu < 2; ++ksu) {
            short8 af[4], bfr[4];
            #pragma unroll
            for (int i = 0; i < 4; ++i) {
                af[i]  = *(const short8*)pA[ksu][i];
                bfr[i] = *(const short8*)pB[ksu][i];
            }
            #pragma unroll
            for (int i = 0; i < 4; ++i)
                #pragma unroll
                for (int j = 0; j < 4; ++j)
                    acc[i][j] = __builtin_amdgcn_mfma_f32_16x16x32_bf16(af[i], bfr[j], acc[i][j], 0, 0, 0);
        }
        __syncthreads();
    }

    #pragma unroll
    for (int i = 0; i < 4; ++i) {
        #pragma unroll
        for (int j = 0; j < 4; ++j) {
            int rowb = m0 + wrow * 64 + i * 16 + quad * 4;
            int col  = n0 + wcol * 64 + j * 16 + lm;
            if (EPI == EPI_QKV) {
                int b = rowb >> 12, seq = rowb & (NN - 1);
                int which = col >> 9, rem = col & 511;
                int h = rem >> 6, dd = rem & 63;
                int bh = b * HH + h;
                if (which == 0) {
                    #pragma unroll
                    for (int r = 0; r < 4; ++r)
                        qb[((long)bh * NN + seq + r) * DD + dd] = __float2bfloat16(acc[i][j][r] * 0.125f);
                } else if (which == 1) {
                    #pragma unroll
                    for (int r = 0; r < 4; ++r)
                        kb[((long)bh * NN + seq + r) * DD + dd] = __float2bfloat16(acc[i][j][r]);
                } else {
                    union { unsigned long long u; unsigned short s[4]; } pk;
                    #pragma unroll
                    for (int r = 0; r < 4; ++r) pk.s[r] = bf16_bits(acc[i][j][r]);
                    *(unsigned long long*)&vtb[((long)bh * DD + dd) * NN + seq] = pk.u;
                }
            } else { // EPI_OUT
                #pragma unroll
                for (int r = 0; r < 4; ++r) {
                    int row = rowb + r;
                    C[(long)row * N + col] = acc[i][j][r] + bias[col] + resid[(long)row * N + col];
                }
            }
        }
    }
}

// ---------------------------------------------------------------------------
// Batched bf16 MFMA GEMM for pinv: 32 batches of 256x256x256, 64x64 tile,
// grid (4,4,32)=512 blocks. XCD-chunk swizzle. Direct packed epilogue.
__launch_bounds__(256)
__global__ void gemm_pinv(const __hip_bfloat16* __restrict__ A,
                          const __hip_bfloat16* __restrict__ Bt,
                          __hip_bfloat16* __restrict__ CnBf,
                          float* __restrict__ CnF,
                          __hip_bfloat16* __restrict__ CTbf,
                          float diag, float sgn, float scale) {
    __shared__ __hip_bfloat16 As[64][256];
    __shared__ __hip_bfloat16 Bs[64][256];
    const int t = threadIdx.x;
    const int hw = (blockIdx.z * 4 + blockIdx.y) * 4 + blockIdx.x;
    const int lg = xcd_swz(hw, 512);
    const long base = (long)(lg >> 4) << 16;
    const int m0 = ((lg >> 2) & 3) * 64, n0 = (lg & 3) * 64;
    const int wave = t >> 6, lane = t & 63;
    const int wr = wave >> 1, wc = wave & 1;
    const int lm = lane & 15, quad = lane >> 4;
    const __hip_bfloat16* Ab = A + base;
    const __hip_bfloat16* Bb = Bt + base;

    #pragma unroll
    for (int p = 0; p < 8; ++p) {
        int idx = t + p * 256;                 // 0..2047
        int r = idx >> 5;                      // row 0..63
        int csrc = ((idx & 31) ^ (r & 7)) * 8; // swizzled source chunk (elems)
        int cb = idx * 8;                      // linear LDS elem offset
        gl_lds16(&Ab[(long)(m0 + r) * 256 + csrc], &As[0][0] + cb);
        gl_lds16(&Bb[(long)(n0 + r) * 256 + csrc], &Bs[0][0] + cb);
    }

    // per-parity swizzled read bases; higher K-bits walk at +128B compile-time
    const char* pA[2][2];
    const char* pB[2][2];
    #pragma unroll
    for (int i = 0; i < 2; ++i) {
        int ra = wr * 32 + i * 16 + lm;
        int rb = wc * 32 + i * 16 + lm;
        int ca = quad ^ (ra & 3), ra2 = (ra >> 2) & 1;
        int cb2 = quad ^ (rb & 3), rb2 = (rb >> 2) & 1;
        pA[0][i] = (const char*)&As[ra][(4 * ra2       + ca)  * 8];
        pA[1][i] = (const char*)&As[ra][(4 * (1 - ra2) + ca)  * 8];
        pB[0][i] = (const char*)&Bs[rb][(4 * rb2       + cb2) * 8];
        pB[1][i] = (const char*)&Bs[rb][(4 * (1 - rb2) + cb2) * 8];
    }
    __syncthreads();

    float4v acc[2][2] = {};
    #pragma unroll
    for (int ksu = 0; ksu < 8; ++ksu) {
        short8 af[2], bfr[2];
        #pragma unroll
        for (int i = 0; i < 2; ++i) {
            af[i]  = *(const short8*)(pA[ksu & 1][i] + (ksu >> 1) * 128);
            bfr[i] = *(const short8*)(pB[ksu & 1][i] + (ksu >> 1) * 128);
        }
        #pragma unroll
        for (int i = 0; i < 2; ++i)
            #pragma unroll
            for (int j = 0; j < 2; ++j)
                acc[i][j] = __builtin_amdgcn_mfma_f32_16x16x32_bf16(af[i], bfr[j], acc[i][j], 0, 0, 0);
    }

    #pragma unroll
    for (int i = 0; i < 2; ++i)
        #pragma unroll
        for (int j = 0; j < 2; ++j) {
            const int rowb = wr * 32 + i * 16 + quad * 4;   // 4 consecutive rows
            const int col  = wc * 32 + j * 16 + lm;
            union { unsigned long long u; unsigned short s[4]; } pk;
            #pragma unroll
            for (int r = 0; r < 4; ++r) {
                float v = acc[i][j][r] * scale;
                long off = base + (long)(m0 + rowb + r) * 256 + n0 + col;
                if (CnBf) CnBf[off] = __float2bfloat16(v);
                if (CnF)  CnF[off]  = v;
                float tv = sgn * v + ((m0 + rowb + r) == (n0 + col) ? diag : 0.0f);
                pk.s[r] = bf16_bits(tv);
            }
            if (CTbf)
                *(unsigned long long*)&CTbf[base + (long)(n0 + col) * 256 + m0 + rowb] = pk.u;
        }
}

// ---------------------------------------------------------------------------
// Dual batched pinv GEMM (round-12): computes BOTH z' = 0.25 z @ t3 and
// P' = 0.25 P @ t3 in ONE launch (the az-recurrence az' = 0.25 P t3 replaces
// next iteration's a2@z' GEMM). 1024 blocks = 32 pairs x {z-half, P-half} x 16
// tiles; both halves of a pair share the t3T panel, kept adjacent for L2.
// P-half epilogue also emits t1'^T = (7I - P')^T for the next iteration.
__launch_bounds__(256)
__global__ void gemm_pinv2(const __hip_bfloat16* __restrict__ zA,
                           const __hip_bfloat16* __restrict__ pAg,
                           const __hip_bfloat16* __restrict__ t3T,
                           __hip_bfloat16* __restrict__ zOut,
                           float* __restrict__ zF,
                           __hip_bfloat16* __restrict__ pOut,
                           __hip_bfloat16* __restrict__ t1T) {
    __shared__ __hip_bfloat16 As[64][256];
    __shared__ __hip_bfloat16 Bs[64][256];
    const int t = threadIdx.x;
    const int hw = blockIdx.y * 16 + blockIdx.x;     // grid (16, 64)
    const int lg = xcd_swz(hw, 1024);
    const int pair = lg >> 5;                        // batch 0..31
    const int half = (lg >> 4) & 1;                  // 0 = z, 1 = P
    const int tile = lg & 15;
    const long base = (long)pair << 16;
    const int m0 = (tile >> 2) * 64, n0 = (tile & 3) * 64;
    const int wave = t >> 6, lane = t & 63;
    const int wr = wave >> 1, wc = wave & 1;
    const int lm = lane & 15, quad = lane >> 4;
    const __hip_bfloat16* Ab = (half ? pAg : zA) + base;
    const __hip_bfloat16* Bb = t3T + base;

    #pragma unroll
    for (int p = 0; p < 8; ++p) {
        int idx = t + p * 256;
        int r = idx >> 5;
        int csrc = ((idx & 31) ^ (r & 7)) * 8;
        int cb = idx * 8;
        gl_lds16(&Ab[(long)(m0 + r) * 256 + csrc], &As[0][0] + cb);
        gl_lds16(&Bb[(long)(n0 + r) * 256 + csrc], &Bs[0][0] + cb);
    }

    const char* pA[2][2];
    const char* pB[2][2];
    #pragma unroll
    for (int i = 0; i < 2; ++i) {
        int ra = wr * 32 + i * 16 + lm;
        int rb = wc * 32 + i * 16 + lm;
        int ca = quad ^ (ra & 3), ra2 = (ra >> 2) & 1;
        int cb2 = quad ^ (rb & 3), rb2 = (rb >> 2) & 1;
        pA[0][i] = (const char*)&As[ra][(4 * ra2       + ca)  * 8];
        pA[1][i] = (const char*)&As[ra][(4 * (1 - ra2) + ca)  * 8];
        pB[0][i] = (const char*)&Bs[rb][(4 * rb2       + cb2) * 8];
        pB[1][i] = (const char*)&Bs[rb][(4 * (1 - rb2) + cb2) * 8];
    }
    __syncthreads();

    float4v acc[2][2] = {};
    #pragma unroll
    for (int ksu = 0; ksu < 8; ++ksu) {
        short8 af[2], bfr[2];
        #pragma unroll
        for (int i = 0; i < 2; ++i) {
            af[i]  = *(const short8*)(pA[ksu & 1][i] + (ksu >> 1) * 128);
            bfr[i] = *(const short8*)(pB[ksu & 1][i] + (ksu >> 1) * 128);
        }
        #pragma unroll
        for (int i = 0; i < 2; ++i)
            #pragma unroll
            for (int j = 0; j < 2; ++j)
                acc[i][j] = __builtin_amdgcn_mfma_f32_16x16x32_bf16(af[i], bfr[j], acc[i][j], 0, 0, 0);
    }

    #pragma unroll
    for (int i = 0; i < 2; ++i)
        #pragma unroll
        for (int j = 0; j < 2; ++j) {
            const int rowb = wr * 32 + i * 16 + quad * 4;
            const int col  = wc * 32 + j * 16 + lm;
            union { unsigned long long u; unsigned short s[4]; } pk;
            #pragma unroll
            for (int r = 0; r < 4; ++r) {
                float v = acc[i][j][r] * 0.25f;
                long off = base + (long)(m0 + rowb + r) * 256 + n0 + col;
                if (half == 0) {
                    zOut[off] = __float2bfloat16(v);
                    if (zF) zF[off] = v;
                } else {
                    pOut[off] = __float2bfloat16(v);
                    float tv = -v + ((m0 + rowb + r) == (n0 + col) ? 7.0f : 0.0f);
                    pk.s[r] = bf16_bits(tv);
                }
            }
            if (half)
                *(unsigned long long*)&t1T[base + (long)(n0 + col) * 256 + m0 + rowb] = pk.u;
        }
}

// ---------------------------------------------------------------------------
// pinv prep: a2_bf = bf16(a2); z0T = bf16(s*a2); z0n = bf16(s*a2^T). grid (4,4,32).
__launch_bounds__(256)
__global__ void pinv_prep(const float* __restrict__ a2, const float* __restrict__ scl,
                          __hip_bfloat16* __restrict__ a2bf, __hip_bfloat16* __restrict__ z0T,
                          __hip_bfloat16* __restrict__ z0n) {
    __shared__ float tl[64][65];
    const int t = threadIdx.x;
    const long base = (long)blockIdx.z << 16;
    const int i0 = blockIdx.y * 64, j0 = blockIdx.x * 64;
    float s = scl[0];
    #pragma unroll
    for (int p = 0; p < 16; ++p) {
        int idx = t + p * 256;
        int r = idx >> 6, c = idx & 63;
        long off = base + (long)(i0 + r) * 256 + j0 + c;
        float v = a2[off];
        a2bf[off] = __float2bfloat16(v);
        float zv = v * s;
        z0T[off] = __float2bfloat16(zv);
        tl[r][c] = zv;
    }
    __syncthreads();
    int r = t & 63;
    #pragma unroll
    for (int u = 0; u < 16; ++u) {
        int c = u * 4 + (t >> 6);
        z0n[base + (long)(j0 + c) * 256 + i0 + r] = __float2bfloat16(tl[r][c]);
    }
}

// ---------------------------------------------------------------------------
// Generic fp32 tiled GEMM (sim2 / wm). 64x64 tile, BK=16. XCD-chunk swizzled.
template<int EPI, bool TRANSB>
__launch_bounds__(256)
__global__ void gemm64(const float* __restrict__ A, const float* __restrict__ Bm,
                       float* __restrict__ C,
                       int M, int N, int K, long sA, long sB, long sC, float alpha) {
    const int gx = gridDim.x, gxy = gridDim.x * gridDim.y;
    const int hw = blockIdx.z * gxy + blockIdx.y * gx + blockIdx.x;
    const int lg = xcd_swz(hw, gxy * gridDim.z);
    const int bz = lg / gxy;
    const int rem = lg % gxy;
    const float* Ab = A + (long)bz * sA;
    const float* Bb = Bm + (long)bz * sB;
    float* Cb = C + (long)bz * sC;

    __shared__ float As[16][64];
    __shared__ float Bs[16][64];

    const int tid = threadIdx.x;
    const int tx = tid & 15;
    const int ty = tid >> 4;
    const int m0 = (rem / gx) * 64;
    const int n0 = (rem % gx) * 64;

    float acc[4][4] = {};

    for (int k0 = 0; k0 < K; k0 += 16) {
        {
            int r  = tid >> 2;
            int kk = (tid & 3) * 4;
            float4 va = *(const float4*)(Ab + (long)(m0 + r) * K + k0 + kk);
            As[kk + 0][r] = va.x; As[kk + 1][r] = va.y; As[kk + 2][r] = va.z; As[kk + 3][r] = va.w;
        }
        if (!TRANSB) {
            int kk = tid >> 4;
            int j  = (tid & 15) * 4;
            float4 vb = *(const float4*)(Bb + (long)(k0 + kk) * N + n0 + j);
            Bs[kk][j + 0] = vb.x; Bs[kk][j + 1] = vb.y; Bs[kk][j + 2] = vb.z; Bs[kk][j + 3] = vb.w;
        } else {
            int j  = tid >> 2;
            int kk = (tid & 3) * 4;
            float4 vb = *(const float4*)(Bb + (long)(n0 + j) * K + k0 + kk);
            Bs[kk + 0][j] = vb.x; Bs[kk + 1][j] = vb.y; Bs[kk + 2][j] = vb.z; Bs[kk + 3][j] = vb.w;
        }
        __syncthreads();
        #pragma unroll
        for (int kk = 0; kk < 16; ++kk) {
            float a0 = As[kk][ty * 4 + 0], a1 = As[kk][ty * 4 + 1];
            float a2 = As[kk][ty * 4 + 2], a3 = As[kk][ty * 4 + 3];
            float b0 = Bs[kk][tx * 4 + 0], b1 = Bs[kk][tx * 4 + 1];
            float b2 = Bs[kk][tx * 4 + 2], b3 = Bs[kk][tx * 4 + 3];
            acc[0][0] += a0 * b0; acc[0][1] += a0 * b1; acc[0][2] += a0 * b2; acc[0][3] += a0 * b3;
            acc[1][0] += a1 * b0; acc[1][1] += a1 * b1; acc[1][2] += a1 * b2; acc[1][3] += a1 * b3;
            acc[2][0] += a2 * b0; acc[2][1] += a2 * b1; acc[2][2] += a2 * b2; acc[2][3] += a2 * b3;
            acc[3][0] += a3 * b0; acc[3][1] += a3 * b1; acc[3][2] += a3 * b2; acc[3][3] += a3 * b3;
        }
        __syncthreads();
    }

    #pragma unroll
    for (int r = 0; r < 4; ++r)
        #pragma unroll
        for (int c = 0; c < 4; ++c)
            Cb[(long)(m0 + ty * 4 + r) * N + n0 + tx * 4 + c] = acc[r][c] * alpha;
}

// ---------------------------------------------------------------------------
// Landmark means from bf16 q/k; writes fp32 (for sim2) and bf16 (for MFMA flash).
__global__ void landmark_kernel(const __hip_bfloat16* __restrict__ qb,
                                const __hip_bfloat16* __restrict__ kb,
                                float* __restrict__ q_l, float* __restrict__ k_l,
                                __hip_bfloat16* __restrict__ q_lb,
                                __hip_bfloat16* __restrict__ k_lb) {
    int bh = blockIdx.x >> 8;
    int m  = blockIdx.x & 255;
    int d  = threadIdx.x;     // 64
    const __hip_bfloat16* src = (blockIdx.y ? kb : qb) + ((long)bh * NN + m * LL) * DD + d;
    float s = 0.f;
    #pragma unroll
    for (int t = 0; t < LL; ++t) s += __bfloat162float(src[(long)t * DD]);
    s *= (1.0f / LL);
    long off = ((long)bh * MM + m) * DD + d;
    if (blockIdx.y) { k_l[off] = s; k_lb[off] = __float2bfloat16(s); }
    else            { q_l[off] = s; q_lb[off] = __float2bfloat16(s); }
}

// ---------------------------------------------------------------------------
__launch_bounds__(256)
__global__ void softmax256_kernel(float* __restrict__ a) {
    long row = blockIdx.x;
    int t = threadIdx.x;
    float* r = a + row * 256;
    float v = r[t];
    __shared__ float red[256];
    red[t] = v;
    __syncthreads();
    for (int off = 128; off > 0; off >>= 1) { if (t < off) red[t] = fmaxf(red[t], red[t + off]); __syncthreads(); }
    float mx = red[0];
    __syncthreads();
    float e = __expf(v - mx);
    red[t] = e;
    __syncthreads();
    for (int off = 128; off > 0; off >>= 1) { if (t < off) red[t] += red[t + off]; __syncthreads(); }
    r[t] = e / red[0];
}

// ---------------------------------------------------------------------------
// Max column-sum of a2 (row-sums are 1.0: softmax rows). 256 blocks.
__launch_bounds__(256)
__global__ void redmax_kernel(const float* __restrict__ a2, float* __restrict__ red) {
    int blk = blockIdx.x;            // bh*8 + cg
    int bh = blk >> 3, cg = blk & 7;
    int t = threadIdx.x;
    const float* Ab = a2 + ((long)bh << 16) + cg * 32;
    int c = t & 31, rg = t >> 5;     // col 0..31, row-group 0..7
    float s = 0.f;
    for (int r = rg * 32; r < rg * 32 + 32; ++r) s += Ab[(long)r * 256 + c];
    __shared__ float m[256];
    m[t] = s;
    __syncthreads();
    if (t < 32) {
        float cs = 0.f;
        #pragma unroll
        for (int g = 0; g < 8; ++g) cs += m[t + 32 * g];
        m[t] = cs;
    }
    __syncthreads();
    if (t == 0) {
        float mx = m[0];
        #pragma unroll
        for (int i = 1; i < 32; ++i) mx = fmaxf(mx, m[i]);
        red[blk] = mx;
    }
}

__launch_bounds__(256)
__global__ void scale_kernel(const float* __restrict__ red, float* __restrict__ scl) {
    __shared__ float b[256];
    int t = threadIdx.x;  // 256
    b[t] = red[t];
    __syncthreads();
    for (int off = 128; off > 0; off >>= 1) {
        if (t < off) b[t] = fmaxf(b[t], b[t + off]);
        __syncthreads();
    }
    if (t == 0) scl[0] = 1.0f / b[0];
}

// ---------------------------------------------------------------------------
// a3v flash MFMA: block = 64 landmark rows x 1024-seq slice (16 chunks of 64).
// K/V register prefetch one chunk ahead + lgkm-only barriers. XCD-swizzled.
__launch_bounds__(256)
__global__ void a3v_mfma(const __hip_bfloat16* __restrict__ qlb,
                         const __hip_bfloat16* __restrict__ kb,
                         const __hip_bfloat16* __restrict__ vtb,
                         float* __restrict__ opart, float* __restrict__ lpart) {
    const int hw = blockIdx.y * 16 + blockIdx.x;
    const int lg = xcd_swz(hw, 512);
    const int bh = lg >> 4;
    const int mt = (lg >> 2) & 3;
    const int ns = lg & 3;
    const int t = threadIdx.x;
    const int wave = t >> 6, lane = t & 63;
    const int wr = wave >> 1, wc = wave & 1;
    const int lm = lane & 15, quad = lane >> 4;
    const int r8 = t >> 3, c8 = (t & 7) * 8;

    __shared__ __hip_bfloat16 Qs[64][72];
    __shared__ __hip_bfloat16 Ks[64][72];
    __shared__ __hip_bfloat16 Vt[64][72];
    __shared__ __hip_bfloat16 Ps[64][72];
    __shared__ float lredS[64][2];

    {
        const __hip_bfloat16* qbase = qlb + ((long)bh * MM + mt * 64) * DD;
        *(uint4*)&Qs[r8][c8]      = *(const uint4*)&qbase[(long)r8 * DD + c8];
        *(uint4*)&Qs[r8 + 32][c8] = *(const uint4*)&qbase[(long)(r8 + 32) * DD + c8];
    }

    float4v acc[2][2] = {};
    float lacc[2][4] = {};
    const __hip_bfloat16* kbase = kb + ((long)bh * NN + ns * 1024) * DD;
    const __hip_bfloat16* vbase = vtb + (long)bh * DD * NN + ns * 1024;

    // prefetch chunk 0 into regs
    uint4 kv0 = *(const uint4*)&kbase[(long)r8 * DD + c8];
    uint4 kv1 = *(const uint4*)&kbase[(long)(r8 + 32) * DD + c8];
    uint4 vv0 = *(const uint4*)&vbase[(long)r8 * NN + c8];
    uint4 vv1 = *(const uint4*)&vbase[(long)(r8 + 32) * NN + c8];
    bar_nv();   // Qs visible; prefetch stays in flight

    for (int ch = 0; ch < 16; ++ch) {
        *(uint4*)&Ks[r8][c8]      = kv0;
        *(uint4*)&Ks[r8 + 32][c8] = kv1;
        *(uint4*)&Vt[r8][c8]      = vv0;
        *(uint4*)&Vt[r8 + 32][c8] = vv1;
        if (ch < 15) {   // issue next chunk's loads; they fly during compute
            kv0 = *(const uint4*)&kbase[(long)((ch + 1) * 64 + r8) * DD + c8];
            kv1 = *(const uint4*)&kbase[(long)((ch + 1) * 64 + r8 + 32) * DD + c8];
            vv0 = *(const uint4*)&vbase[(long)r8 * NN + (ch + 1) * 64 + c8];
            vv1 = *(const uint4*)&vbase[(long)(r8 + 32) * NN + (ch + 1) * 64 + c8];
        }
        bar_nv();

        float4v s[2][2] = {};
        #pragma unroll
        for (int ks = 0; ks < 64; ks += 32) {
            short8 af[2], bfr[2];
            #pragma unroll
            for (int i = 0; i < 2; ++i) {
                af[i]  = *(const short8*)&Qs[wr * 32 + i * 16 + lm][ks + quad * 8];
                bfr[i] = *(const short8*)&Ks[wc * 32 + i * 16 + lm][ks + quad * 8];
            }
            #pragma unroll
            for (int i = 0; i < 2; ++i)
                #pragma unroll
                for (int j = 0; j < 2; ++j)
                    s[i][j] = __builtin_amdgcn_mfma_f32_16x16x32_bf16(af[i], bfr[j], s[i][j], 0, 0, 0);
        }
        #pragma unroll
        for (int i = 0; i < 2; ++i)
            #pragma unroll
            for (int j = 0; j < 2; ++j)
                #pragma unroll
                for (int r2 = 0; r2 < 4; ++r2) {
                    float e = __expf(s[i][j][r2]);
                    lacc[i][r2] += e;
                    Ps[wr * 32 + i * 16 + quad * 4 + r2][wc * 32 + j * 16 + lm] = __float2bfloat16(e);
                }
        bar_nv();

        #pragma unroll
        for (int ks = 0; ks < 64; ks += 32) {
            short8 af[2], bfr[2];
            #pragma unroll
            for (int i = 0; i < 2; ++i) {
                af[i]  = *(const short8*)&Ps[wr * 32 + i * 16 + lm][ks + quad * 8];
                bfr[i] = *(const short8*)&Vt[wc * 32 + i * 16 + lm][ks + quad * 8];
            }
            #pragma unroll
            for (int i = 0; i < 2; ++i)
                #pragma unroll
                for (int j = 0; j < 2; ++j)
                    acc[i][j] = __builtin_amdgcn_mfma_f32_16x16x32_bf16(af[i], bfr[j], acc[i][j], 0, 0, 0);
        }
        bar_nv();
    }

    // wave-level l-sum reduction over the 16 lm lanes
    #pragma unroll
    for (int i = 0; i < 2; ++i)
        #pragma unroll
        for (int r2 = 0; r2 < 4; ++r2) {
            float s = lacc[i][r2];
            s += __shfl_xor(s, 1);
            s += __shfl_xor(s, 2);
            s += __shfl_xor(s, 4);
            s += __shfl_xor(s, 8);
            if (lm == 0) lredS[wr * 32 + i * 16 + quad * 4 + r2][wc] = s;
        }
    __syncthreads();
    if (t < 64)
        lpart[((bh * 4 + mt) * 4 + ns) * 64 + t] = lredS[t][0] + lredS[t][1];
    const long pbase = ((long)((bh * 4 + mt) * 4 + ns)) << 12;
    #pragma unroll
    for (int i = 0; i < 2; ++i)
        #pragma unroll
        for (int j = 0; j < 2; ++j)
            #pragma unroll
            for (int r2 = 0; r2 < 4; ++r2)
                opart[pbase + (long)(wr * 32 + i * 16 + quad * 4 + r2) * 64 + wc * 32 + j * 16 + lm] = acc[i][j][r2];
}

// stage 2: combine 4 n-split partials
__global__ void a3v_combine(const float* __restrict__ opart, const float* __restrict__ lpart,
                            float* __restrict__ a3v) {
    int idx = blockIdx.x * 256 + threadIdx.x;
    int d  = idx & 63;
    int m  = (idx >> 6) & 255;
    int bh = idx >> 14;
    int mt = m >> 6, r = m & 63;
    int pb = (bh * 4 + mt) * 4;
    float osum = 0.f, lsum = 0.f;
    #pragma unroll
    for (int ns = 0; ns < 4; ++ns) {
        osum += opart[(((long)(pb + ns)) << 12) + r * 64 + d];
        lsum += lpart[(pb + ns) * 64 + r];
    }
    a3v[((long)bh * MM + m) * DD + d] = osum / lsum;
}

// ---------------------------------------------------------------------------
// wm transpose -> bf16: wtb[bh][dd][m] = bf16(wm[bh][m][dd]). One block per bh.
__launch_bounds__(256)
__global__ void wmT_kernel(const float* __restrict__ wm, __hip_bfloat16* __restrict__ wtb) {
    __shared__ float tile[64][65];
    const int bh = blockIdx.x;
    const int t = threadIdx.x;
    for (int mc = 0; mc < 4; ++mc) {
        #pragma unroll
        for (int p = 0; p < 16; ++p) {
            int idx = t + p * 256;
            int r = idx >> 6, c = idx & 63;
            tile[r][c] = wm[((long)bh * MM + mc * 64 + r) * DD + c];
        }
        __syncthreads();
        #pragma unroll
        for (int p = 0; p < 16; ++p) {
            int idx = t + p * 256;
            int dd = idx >> 6, m = idx & 63;
            wtb[((long)bh * DD + dd) * MM + mc * 64 + m] = __float2bfloat16(tile[m][dd]);
        }
        __syncthreads();
    }
}

// ---------------------------------------------------------------------------
// attn_out flash MFMA + Toeplitz-MFMA depthwise conv. XCD-swizzled.
__launch_bounds__(256)
__global__ void attn_out_mfma(const __hip_bfloat16* __restrict__ qb,
                              const __hip_bfloat16* __restrict__ klb,
                              const __hip_bfloat16* __restrict__ wtb,
                              const __hip_bfloat16* __restrict__ vtb,
                              const float* __restrict__ convw,
                              __hip_bfloat16* __restrict__ ctx) {
    const int hw = blockIdx.y * 64 + blockIdx.x;
    const int lg = xcd_swz(hw, 2048);
    const int bh = lg >> 6;
    const int b = bh >> 3, h = bh & 7;
    const int i0 = (lg & 63) * 64;
    const int t = threadIdx.x;
    const int wave = t >> 6, lane = t & 63;
    const int wr = wave >> 1, wc = wave & 1;
    const int lm = lane & 15, quad = lane >> 4;
    const int r8 = t >> 3, c8 = (t & 7) * 8;

    __shared__ __hip_bfloat16 Qs[64][72];
    __shared__ __hip_bfloat16 KW[2][64][72];   // Ks = KW[0], Wt = KW[1]; Tpl aliases
    __shared__ __hip_bfloat16 Ps[64][72];
    __shared__ __hip_bfloat16 Vc[64][104];     // v window [i0-16, i0+80): cols 0..95
    __shared__ float lredS[64][2];
    __shared__ float dsum[64];
    __shared__ float cwS[KS];
    __hip_bfloat16 (*Tpl)[104] = reinterpret_cast<__hip_bfloat16 (*)[104]>(&KW[0][0][0]);

    if (t < KS) cwS[t] = convw[h * KS + t];

    {   // stage Q tile
        const __hip_bfloat16* qbase = qb + ((long)bh * NN + i0) * DD;
        *(uint4*)&Qs[r8][c8]      = *(const uint4*)&qbase[(long)r8 * DD + c8];
        *(uint4*)&Qs[r8 + 32][c8] = *(const uint4*)&qbase[(long)(r8 + 32) * DD + c8];
    }
    {   // stage V conv window: 64 dd x 12 chunks of 8 bf16
        for (int c = t; c < 768; c += 256) {
            int dd = c / 12, u = c - dd * 12;
            int g0 = i0 - 16 + u * 8;
            const __hip_bfloat16* vrow = vtb + ((long)bh * DD + dd) * NN;
            __align__(16) __hip_bfloat16 tmp[8];
            if (g0 >= 0 && g0 + 8 <= NN) {
                *(uint4*)tmp = *(const uint4*)&vrow[g0];
            } else {
                #pragma unroll
                for (int e = 0; e < 8; ++e) {
                    int g = g0 + e;
                    tmp[e] = (g >= 0 && g < NN) ? vrow[g] : __float2bfloat16(0.f);
                }
            }
            *(uint4*)&Vc[dd][u * 8] = *(uint4*)tmp;
        }
    }
    __syncthreads();   // cwS, Qs, Vc visible

    {   // build Toeplitz matrix in the Ks/Wt space: T[r][c] = w[c-r], 0 <= c-r < 33
        int r  = t >> 2;            // 0..63
        int c0 = (t & 3) * 24;      // 4 col-groups of 24
        #pragma unroll
        for (int u = 0; u < 12; ++u) {
            int c = c0 + u * 2;
            int d0 = c - r, d1 = c + 1 - r;
            unsigned short lo = (d0 >= 0 && d0 < KS) ? bf16_bits(cwS[d0]) : (unsigned short)0;
            unsigned short hi = (d1 >= 0 && d1 < KS) ? bf16_bits(cwS[d1]) : (unsigned short)0;
            *(unsigned*)&Tpl[r][c] = ((unsigned)hi << 16) | lo;
        }
    }
    bar_nv();          // Tpl visible

    // prefetch chunk 0's K/W into regs: latency hides under the conv MFMAs
    const __hip_bfloat16* klbase = klb + (long)bh * MM * DD;
    const __hip_bfloat16* wbase  = wtb + (long)bh * DD * MM;
    uint4 kv0 = *(const uint4*)&klbase[(long)r8 * DD + c8];
    uint4 kv1 = *(const uint4*)&klbase[(long)(r8 + 32) * DD + c8];
    uint4 wv0 = *(const uint4*)&wbase[(long)r8 * MM + c8];
    uint4 wv1 = *(const uint4*)&wbase[(long)(r8 + 32) * MM + c8];

    // conv via Toeplitz MFMA: accC[row][dd] = sum_s T[row][s] * Vc[dd][s]
    float4v accC[2][2] = {};
    #pragma unroll
    for (int ks = 0; ks < 96; ks += 32) {
        short8 af[2], bfr[2];
        #pragma unroll
        for (int i = 0; i < 2; ++i) {
            af[i]  = *(const short8*)&Tpl[wr * 32 + i * 16 + lm][ks + quad * 8];
            bfr[i] = *(const short8*)&Vc[wc * 32 + i * 16 + lm][ks + quad * 8];
        }
        #pragma unroll
        for (int i = 0; i < 2; ++i)
            #pragma unroll
            for (int j = 0; j < 2; ++j)
                accC[i][j] = __builtin_amdgcn_mfma_f32_16x16x32_bf16(af[i], bfr[j], accC[i][j], 0, 0, 0);
    }
    bar_nv();          // conv reads done; KW space free for K/W staging

    float4v acc[2][2] = {};
    float lacc[2][4] = {};

    for (int ch = 0; ch < 4; ++ch) {
        *(uint4*)&KW[0][r8][c8]      = kv0;
        *(uint4*)&KW[0][r8 + 32][c8] = kv1;
        *(uint4*)&KW[1][r8][c8]      = wv0;
        *(uint4*)&KW[1][r8 + 32][c8] = wv1;
        if (ch < 3) {   // next chunk's loads fly during this chunk's compute
            kv0 = *(const uint4*)&klbase[(long)((ch + 1) * 64 + r8) * DD + c8];
            kv1 = *(const uint4*)&klbase[(long)((ch + 1) * 64 + r8 + 32) * DD + c8];
            wv0 = *(const uint4*)&wbase[(long)r8 * MM + (ch + 1) * 64 + c8];
            wv1 = *(const uint4*)&wbase[(long)(r8 + 32) * MM + (ch + 1) * 64 + c8];
        }
        bar_nv();

        float4v s[2][2] = {};
        #pragma unroll
        for (int ks = 0; ks < 64; ks += 32) {
            short8 af[2], bfr[2];
            #pragma unroll
            for (int i = 0; i < 2; ++i) {
                af[i]  = *(const short8*)&Qs[wr * 32 + i * 16 + lm][ks + quad * 8];
                bfr[i] = *(const short8*)&KW[0][wc * 32 + i * 16 + lm][ks + quad * 8];
            }
            #pragma unroll
            for (int i = 0; i < 2; ++i)
                #pragma unroll
                for (int j = 0; j < 2; ++j)
                    s[i][j] = __builtin_amdgcn_mfma_f32_16x16x32_bf16(af[i], bfr[j], s[i][j], 0, 0, 0);
        }
        #pragma unroll
        for (int i = 0; i < 2; ++i)
            #pragma unroll
            for (int j = 0; j < 2; ++j)
                #pragma unroll
                for (int r2 = 0; r2 < 4; ++r2) {
                    float e = __expf(s[i][j][r2]);
                    lacc[i][r2] += e;
                    Ps[wr * 32 + i * 16 + quad * 4 + r2][wc * 32 + j * 16 + lm] = __float2bfloat16(e);
                }
        bar_nv();

        #pragma unroll
        for (int ks = 0; ks < 64; ks += 32) {
            short8 af[2], bfr[2];
            #pragma unroll
            for (int i = 0; i < 2; ++i) {
                af[i]  = *(const short8*)&Ps[wr * 32 + i * 16 + lm][ks + quad * 8];
                bfr[i] = *(const short8*)&KW[1][wc * 32 + i * 16 + lm][ks + quad * 8];
            }
            #pragma unroll
            for (int i = 0; i < 2; ++i)
                #pragma unroll
                for (int j = 0; j < 2; ++j)
                    acc[i][j] = __builtin_amdgcn_mfma_f32_16x16x32_bf16(af[i], bfr[j], acc[i][j], 0, 0, 0);
        }
        bar_nv();
    }

    // wave-level l-sum reduction over the 16 lm lanes
    #pragma unroll
    for (int i = 0; i < 2; ++i)
        #pragma unroll
        for (int r2 = 0; r2 < 4; ++r2) {
            float s = lacc[i][r2];
            s += __shfl_xor(s, 1);
            s += __shfl_xor(s, 2);
            s += __shfl_xor(s, 4);
            s += __shfl_xor(s, 8);
            if (lm == 0) lredS[wr * 32 + i * 16 + quad * 4 + r2][wc] = s;
        }
    __syncthreads();
    if (t < 64) dsum[t] = 1.0f / (lredS[t][0] + lredS[t][1]);
    __syncthreads();

    // epilogue: normalize + add conv + single ctx write
    #pragma unroll
    for (int j = 0; j < 2; ++j) {
        int dd = wc * 32 + j * 16 + lm;
        #pragma unroll
        for (int i = 0; i < 2; ++i) {
            int R = wr * 32 + i * 16 + quad * 4;
            #pragma unroll
            for (int r2 = 0; r2 < 4; ++r2) {
                int row = R + r2;
                ctx[((long)b * NN + i0 + row) * DIMM + h * DD + dd] =
                    __float2bfloat16(acc[i][j][r2] * dsum[row] + accC[i][j][r2]);
            }
        }
    }
}

// ---------------------------------------------------------------------------
extern "C" void kernel_launch(void* const* d_in, const int* in_sizes, int n_in,
                              void* d_out, int out_size, void* d_ws, size_t ws_size,
                              hipStream_t stream) {
    const float* x      = (const float*)d_in[0];
    const float* norm_w = (const float*)d_in[1];
    const float* norm_b = (const float*)d_in[2];
    const float* Wqkv   = (const float*)d_in[3];
    const float* Wout   = (const float*)d_in[4];
    const float* bout   = (const float*)d_in[5];
    const float* conv_w = (const float*)d_in[6];
    float* out = (float*)d_out;

    float* ws = (float*)d_ws;
    size_t o = 0;
    auto alloc = [&](size_t n) { float* p = ws + o; o += n; return p; };
    auto allocb = [&](size_t n) { return (__hip_bfloat16*)alloc((n + 1) / 2); };

    __hip_bfloat16* xn_bf  = allocb((size_t)NROW * DIMM);
    __hip_bfloat16* wqt_bf = allocb((size_t)3 * DIMM * DIMM);
    __hip_bfloat16* wot_bf = allocb((size_t)DIMM * DIMM);
    __hip_bfloat16* ctx_bf = allocb((size_t)NROW * DIMM);
    __hip_bfloat16* q_bf   = allocb((size_t)BHH * NN * DD);
    __hip_bfloat16* k_bf   = allocb((size_t)BHH * NN * DD);
    __hip_bfloat16* vt_bf  = allocb((size_t)BHH * DD * NN);
    __hip_bfloat16* qlb    = allocb((size_t)BHH * MM * DD);
    __hip_bfloat16* klb    = allocb((size_t)BHH * MM * DD);
    __hip_bfloat16* wt_bf  = allocb((size_t)BHH * DD * MM);
    float* q_l  = alloc((size_t)BHH * MM * DD);
    float* k_l  = alloc((size_t)BHH * MM * DD);
    float* a2   = alloc((size_t)BHH * MM * MM);
    float* zb   = alloc((size_t)BHH * MM * MM);
    float* az   = alloc((size_t)BHH * MM * MM);
    float* gb   = alloc((size_t)BHH * MM * MM);
    float* tb   = alloc((size_t)BHH * MM * MM);
    float* z2   = alloc((size_t)BHH * MM * MM);
    float* a3v  = alloc((size_t)BHH * MM * DD);
    float* wm   = alloc((size_t)BHH * MM * DD);
    float* opart = alloc((size_t)BHH * 4 * 4 * 64 * 64);
    float* lpart = alloc((size_t)BHH * 4 * 4 * 64);
    float* red  = alloc(256);
    float* scl  = alloc(64);

    // bf16 pinv slots (each 2M bf16 = one half of a 4MB fp32 buffer):
    // s0 a2bf (later P ping-B), s1 z0T (later t1T ping-B), s2 z0n / z ping-A,
    // s3 z ping-B, s4 P ping-A, s5 t1T ping-A, s6 t2T, s7 t3T.
    const size_t HB = 1048576;
    __hip_bfloat16* a2bf = (__hip_bfloat16*)az;          // s0
    __hip_bfloat16* z0Tb = (__hip_bfloat16*)(az + HB);   // s1
    __hip_bfloat16* zpA  = (__hip_bfloat16*)gb;          // s2
    __hip_bfloat16* zpB  = (__hip_bfloat16*)(gb + HB);   // s3
    __hip_bfloat16* PnA  = (__hip_bfloat16*)tb;          // s4
    __hip_bfloat16* t1A  = (__hip_bfloat16*)(tb + HB);   // s5
    __hip_bfloat16* t2T  = (__hip_bfloat16*)z2;          // s6
    __hip_bfloat16* t3Tb = (__hip_bfloat16*)(z2 + HB);   // s7

    // 1. LayerNorm -> bf16
    ln_kernel<<<NROW, 256, 0, stream>>>(x, norm_w, norm_b, xn_bf);

    // 1b. transpose+convert weights
    transpose_bf16<<<dim3(3 * DIMM / 32, DIMM / 32), 256, 0, stream>>>(Wqkv, wqt_bf, DIMM, 3 * DIMM);
    transpose_bf16<<<dim3(DIMM / 32, DIMM / 32), 256, 0, stream>>>(Wout, wot_bf, DIMM, DIMM);

    // 2. QKV GEMM (MFMA): q,k bf16 natural; v transposed bf16
    gemm_mfma<EPI_QKV><<<dim3(3 * DIMM / 128, NROW / 128), 256, 0, stream>>>(
        xn_bf, wqt_bf, nullptr, NROW, 3 * DIMM, DIMM,
        nullptr, nullptr, q_bf, k_bf, vt_bf);

    // 3. Landmarks (fp32 + bf16)
    landmark_kernel<<<dim3(BHH * MM, 2), 64, 0, stream>>>(q_bf, k_bf, q_l, k_l, qlb, klb);

    // 4. sim2 = q_l @ k_l^T (fp32)
    gemm64<EPI_NONE, true><<<dim3(4, 4, BHH), 256, 0, stream>>>(
        q_l, k_l, a2, MM, MM, DD, (long)MM * DD, (long)MM * DD, (long)MM * MM, 1.0f);

    // 5. softmax rows -> a2
    softmax256_kernel<<<BHH * MM, 256, 0, stream>>>(a2);

    // 6-7. pinv normalization scalar (max col-sum; row-sums are 1)
    redmax_kernel<<<BHH * 8, 256, 0, stream>>>(a2, red);
    scale_kernel<<<1, 256, 0, stream>>>(red, scl);

    // 8. pinv prep: a2bf, z0T (=s*a2, Bt of P0), z0n (=s*a2^T, z ping-A)
    dim3 g512(4, 4, BHH);
    pinv_prep<<<g512, 256, 0, stream>>>(a2, scl, a2bf, z0Tb, zpA);

    // 9. Newton-Schulz with az-recurrence: P = a2@z tracked directly.
    //    P0 = a2 @ z0 (emits t1 = 7I-P0 transposed); per iteration only 3
    //    launches: t2 = 15I-P@t1, t3 = 13I-P@t2, then the DUAL launch
    //    {z' = 0.25 z@t3 ; P' = 0.25 P@t3 (+ t1' = 7I-P')}. 19 launches vs 24.
    gemm_pinv<<<g512, 256, 0, stream>>>(a2bf, z0Tb, PnA, nullptr, t1A, 7.0f, -1.0f, 1.0f);
    __hip_bfloat16 *zi = zpA, *zo = zpB;
    __hip_bfloat16 *Pc = PnA, *Pn2 = a2bf;    // a2bf slot free after P0
    __hip_bfloat16 *t1c = t1A, *t1n = z0Tb;   // z0T slot free after P0
    for (int it = 0; it < 6; ++it) {
        gemm_pinv<<<g512, 256, 0, stream>>>(Pc, t1c, nullptr, nullptr, t2T, 15.0f, -1.0f, 1.0f);
        gemm_pinv<<<g512, 256, 0, stream>>>(Pc, t2T, nullptr, nullptr, t3Tb, 13.0f, -1.0f, 1.0f);
        gemm_pinv2<<<dim3(16, 64), 256, 0, stream>>>(zi, Pc, t3Tb, zo,
                                                     (it == 5) ? zb : nullptr, Pn2, t1n);
        __hip_bfloat16* tmp;
        tmp = zi; zi = zo; zo = tmp;
        tmp = Pc; Pc = Pn2; Pn2 = tmp;
        tmp = t1c; t1c = t1n; t1n = tmp;
    }
    // zb = a2_inv (fp32)

    // 10. a3v = softmax(q_l . k^T) @ v   (MFMA flash)
    a3v_mfma<<<dim3(16, BHH), 256, 0, stream>>>(qlb, k_bf, vt_bf, opart, lpart);
    a3v_combine<<<BHH * MM * DD / 256, 256, 0, stream>>>(opart, lpart, a3v);

    // 11. wm = a2_inv @ a3v (fp32), then transpose -> bf16
    gemm64<EPI_NONE, false><<<dim3(1, 4, BHH), 256, 0, stream>>>(
        zb, a3v, wm, MM, DD, MM, (long)MM * MM, (long)MM * DD, (long)MM * DD, 1.0f);
    wmT_kernel<<<BHH, 256, 0, stream>>>(wm, wt_bf);

    // 12. attention out + fused depthwise conv -> bf16 ctx
    attn_out_mfma<<<dim3(NN / 64, BHH), 256, 0, stream>>>(
        q_bf, klb, wt_bf, vt_bf, conv_w, ctx_bf);

    // 13. final: out = x + ctx @ Wout + bout  (MFMA)
    gemm_mfma<EPI_OUT><<<dim3(DIMM / 128, NROW / 128), 256, 0, stream>>>(
        ctx_bf, wot_bf, out, NROW, DIMM, DIMM,
        bout, x, nullptr, nullptr, nullptr);
}

// Round 13
// 381.333 us; speedup vs baseline: 1.0634x; 1.0237x over previous
//
#include <hip/hip_runtime.h>
#include <hip/hip_bf16.h>

// Problem constants
#define BB 4
#define NN 4096
#define DIMM 512
#define HH 8
#define DD 64
#define MM 256
#define LL 16
#define BHH 32
#define NROW (BB*NN)      // 16384
#define KS 33

typedef __attribute__((ext_vector_type(8))) short short8;   // 8 bf16 = 4 VGPR
typedef __attribute__((ext_vector_type(4))) float float4v;  // MFMA C/D

static __device__ __forceinline__ unsigned short bf16_bits(float v) {
    __hip_bfloat16 h = __float2bfloat16(v);
    return *reinterpret_cast<unsigned short*>(&h);
}

// async global->LDS 16B per lane; lds base must be wave-uniform (lane i lands at +16*i)
static __device__ __forceinline__ void gl_lds16(const void* g, void* l) {
    __builtin_amdgcn_global_load_lds((const __attribute__((address_space(1))) void*)g,
                                     (__attribute__((address_space(3))) void*)l, 16, 0, 0);
}

// barrier that waits LDS ops only — leaves global (vmcnt) prefetch loads in
// flight across the barrier.
static __device__ __forceinline__ void bar_nv() {
    asm volatile("s_waitcnt lgkmcnt(0)\ns_barrier" ::: "memory");
}

// XCD-chunk swizzle (T1): remap so each XCD executes a CONTIGUOUS logical
// range. Bijective iff nwg % 8 == 0 (true for every grid below).
static __device__ __forceinline__ int xcd_swz(int hw, int nwg) {
    return (hw & 7) * (nwg >> 3) + (hw >> 3);
}

// ---------------------------------------------------------------------------
// LayerNorm: one block per row of [16384, 512] -> bf16 output
__launch_bounds__(256)
__global__ void ln_kernel(const float* __restrict__ x,
                          const float* __restrict__ w,
                          const float* __restrict__ bvec,
                          __hip_bfloat16* __restrict__ xn) {
    int row = blockIdx.x;
    int t = threadIdx.x;
    const float* xr = x + (long)row * DIMM;
    float v0 = xr[t];
    float v1 = xr[t + 256];
    __shared__ float red[256];
    red[t] = v0 + v1;
    __syncthreads();
    for (int off = 128; off > 0; off >>= 1) { if (t < off) red[t] += red[t + off]; __syncthreads(); }
    float mu = red[0] * (1.0f / DIMM);
    __syncthreads();
    float d0 = v0 - mu, d1 = v1 - mu;
    red[t] = d0 * d0 + d1 * d1;
    __syncthreads();
    for (int off = 128; off > 0; off >>= 1) { if (t < off) red[t] += red[t + off]; __syncthreads(); }
    float var = red[0] * (1.0f / DIMM);
    float rs = rsqrtf(var + 1e-5f);
    xn[(long)row * DIMM + t]       = __float2bfloat16(d0 * rs * w[t]       + bvec[t]);
    xn[(long)row * DIMM + t + 256] = __float2bfloat16(d1 * rs * w[t + 256] + bvec[t + 256]);
}

// ---------------------------------------------------------------------------
// Transpose + fp32->bf16: out[N][K] = bf16(in[K][N])
__launch_bounds__(256)
__global__ void transpose_bf16(const float* __restrict__ in, __hip_bfloat16* __restrict__ outp,
                               int K, int N) {
    __shared__ float tile[32][33];
    int k0 = blockIdx.y * 32, n0 = blockIdx.x * 32;
    int tx = threadIdx.x & 31, ty = threadIdx.x >> 5;  // ty 0..7
    #pragma unroll
    for (int i = 0; i < 32; i += 8)
        tile[ty + i][tx] = in[(long)(k0 + ty + i) * N + n0 + tx];
    __syncthreads();
    #pragma unroll
    for (int i = 0; i < 32; i += 8)
        outp[(long)(n0 + ty + i) * K + k0 + tx] = __float2bfloat16(tile[tx][ty + i]);
}

// ---------------------------------------------------------------------------
// bf16 MFMA GEMM: C[M,N] = A[M,K]bf16 @ Bt[N,K]bf16^T.
// 128x128 tile, BK=64, 4 waves (2x2), 4x4 16x16x32 frags/wave. 16B-chunk XOR
// swizzle; XCD-chunk block swizzle. Single-buffer (proven best).
enum { EPI_NONE = 0, EPI_QKV = 1, EPI_OUT = 2 };

template<int EPI>
__launch_bounds__(256)
__global__ void gemm_mfma(const __hip_bfloat16* __restrict__ A,
                          const __hip_bfloat16* __restrict__ Bt,
                          float* __restrict__ C, int M, int N, int K,
                          const float* __restrict__ bias,
                          const float* __restrict__ resid,
                          __hip_bfloat16* __restrict__ qb,
                          __hip_bfloat16* __restrict__ kb,
                          __hip_bfloat16* __restrict__ vtb) {
    __shared__ __hip_bfloat16 As[128][64];
    __shared__ __hip_bfloat16 Bs[128][64];
    const int t = threadIdx.x;
    const int hw = blockIdx.y * gridDim.x + blockIdx.x;
    const int lg = xcd_swz(hw, gridDim.x * gridDim.y);
    const int m0 = (lg / gridDim.x) * 128, n0 = (lg % gridDim.x) * 128;
    const int wave = t >> 6, lane = t & 63;
    const int wrow = wave >> 1, wcol = wave & 1;
    const int lm = lane & 15, quad = lane >> 4;
    const int wbase = wave * 64;   // wave's chunk base within a 256-chunk group

    // hoisted staging pointers (bumped +64 elems per K-step)
    const __hip_bfloat16* gA[4];
    const __hip_bfloat16* gB[4];
    __hip_bfloat16* lA[4];
    __hip_bfloat16* lB[4];
    #pragma unroll
    for (int p = 0; p < 4; ++p) {
        int idx = t + p * 256;
        int r = idx >> 3;
        int csrc = ((idx & 7) ^ (r & 7)) * 8;   // swizzled source chunk
        int cb = (p * 256 + wbase) * 8;          // wave-uniform LDS element base
        gA[p] = &A[(long)(m0 + r) * K + csrc];
        gB[p] = &Bt[(long)(n0 + r) * K + csrc];
        lA[p] = &As[0][0] + cb;
        lB[p] = &Bs[0][0] + cb;
    }

    // hoisted swizzled LDS read bases: [ksi parity][fragment]
    const __hip_bfloat16* pA[2][4];
    const __hip_bfloat16* pB[2][4];
    #pragma unroll
    for (int i = 0; i < 4; ++i) {
        int ra = wrow * 64 + i * 16 + lm;
        int rb = wcol * 64 + i * 16 + lm;
        int ca = quad ^ (ra & 3), ra2 = (ra >> 2) & 1;
        int cb2 = quad ^ (rb & 3), rb2 = (rb >> 2) & 1;
        pA[0][i] = &As[ra][(4 * ra2       + ca)  * 8];
        pA[1][i] = &As[ra][(4 * (1 - ra2) + ca)  * 8];
        pB[0][i] = &Bs[rb][(4 * rb2       + cb2) * 8];
        pB[1][i] = &Bs[rb][(4 * (1 - rb2) + cb2) * 8];
    }

    float4v acc[4][4] = {};

    for (int k0 = 0; k0 < K; k0 += 64) {
        #pragma unroll
        for (int p = 0; p < 4; ++p) {
            gl_lds16(gA[p], lA[p]);
            gl_lds16(gB[p], lB[p]);
            gA[p] += 64;
            gB[p] += 64;
        }
        __syncthreads();
        #pragma unroll
        for (int ksu = 0; ksu < 2; ++ksu) {
            short8 af[4], bfr[4];
            #pragma unroll
            for (int i = 0; i < 4; ++i) {
                af[i]  = *(const short8*)pA[ksu][i];
                bfr[i] = *(const short8*)pB[ksu][i];
            }
            #pragma unroll
            for (int i = 0; i < 4; ++i)
                #pragma unroll
                for (int j = 0; j < 4; ++j)
                    acc[i][j] = __builtin_amdgcn_mfma_f32_16x16x32_bf16(af[i], bfr[j], acc[i][j], 0, 0, 0);
        }
        __syncthreads();
    }

    #pragma unroll
    for (int i = 0; i < 4; ++i) {
        #pragma unroll
        for (int j = 0; j < 4; ++j) {
            int rowb = m0 + wrow * 64 + i * 16 + quad * 4;
            int col  = n0 + wcol * 64 + j * 16 + lm;
            if (EPI == EPI_QKV) {
                int b = rowb >> 12, seq = rowb & (NN - 1);
                int which = col >> 9, rem = col & 511;
                int h = rem >> 6, dd = rem & 63;
                int bh = b * HH + h;
                if (which == 0) {
                    #pragma unroll
                    for (int r = 0; r < 4; ++r)
                        qb[((long)bh * NN + seq + r) * DD + dd] = __float2bfloat16(acc[i][j][r] * 0.125f);
                } else if (which == 1) {
                    #pragma unroll
                    for (int r = 0; r < 4; ++r)
                        kb[((long)bh * NN + seq + r) * DD + dd] = __float2bfloat16(acc[i][j][r]);
                } else {
                    union { unsigned long long u; unsigned short s[4]; } pk;
                    #pragma unroll
                    for (int r = 0; r < 4; ++r) pk.s[r] = bf16_bits(acc[i][j][r]);
                    *(unsigned long long*)&vtb[((long)bh * DD + dd) * NN + seq] = pk.u;
                }
            } else { // EPI_OUT
                #pragma unroll
                for (int r = 0; r < 4; ++r) {
                    int row = rowb + r;
                    C[(long)row * N + col] = acc[i][j][r] + bias[col] + resid[(long)row * N + col];
                }
            }
        }
    }
}

// ---------------------------------------------------------------------------
// Batched bf16 MFMA GEMM for pinv: 32 batches of 256x256x256, 64x64 tile,
// grid (4,4,32)=512 blocks. XCD-chunk swizzle. Direct packed epilogue.
__launch_bounds__(256)
__global__ void gemm_pinv(const __hip_bfloat16* __restrict__ A,
                          const __hip_bfloat16* __restrict__ Bt,
                          __hip_bfloat16* __restrict__ CnBf,
                          float* __restrict__ CnF,
                          __hip_bfloat16* __restrict__ CTbf,
                          float diag, float sgn, float scale) {
    __shared__ __hip_bfloat16 As[64][256];
    __shared__ __hip_bfloat16 Bs[64][256];
    const int t = threadIdx.x;
    const int hw = (blockIdx.z * 4 + blockIdx.y) * 4 + blockIdx.x;
    const int lg = xcd_swz(hw, 512);
    const long base = (long)(lg >> 4) << 16;
    const int m0 = ((lg >> 2) & 3) * 64, n0 = (lg & 3) * 64;
    const int wave = t >> 6, lane = t & 63;
    const int wr = wave >> 1, wc = wave & 1;
    const int lm = lane & 15, quad = lane >> 4;
    const __hip_bfloat16* Ab = A + base;
    const __hip_bfloat16* Bb = Bt + base;

    #pragma unroll
    for (int p = 0; p < 8; ++p) {
        int idx = t + p * 256;                 // 0..2047
        int r = idx >> 5;                      // row 0..63
        int csrc = ((idx & 31) ^ (r & 7)) * 8; // swizzled source chunk (elems)
        int cb = idx * 8;                      // linear LDS elem offset
        gl_lds16(&Ab[(long)(m0 + r) * 256 + csrc], &As[0][0] + cb);
        gl_lds16(&Bb[(long)(n0 + r) * 256 + csrc], &Bs[0][0] + cb);
    }

    // per-parity swizzled read bases; higher K-bits walk at +128B compile-time
    const char* pA[2][2];
    const char* pB[2][2];
    #pragma unroll
    for (int i = 0; i < 2; ++i) {
        int ra = wr * 32 + i * 16 + lm;
        int rb = wc * 32 + i * 16 + lm;
        int ca = quad ^ (ra & 3), ra2 = (ra >> 2) & 1;
        int cb2 = quad ^ (rb & 3), rb2 = (rb >> 2) & 1;
        pA[0][i] = (const char*)&As[ra][(4 * ra2       + ca)  * 8];
        pA[1][i] = (const char*)&As[ra][(4 * (1 - ra2) + ca)  * 8];
        pB[0][i] = (const char*)&Bs[rb][(4 * rb2       + cb2) * 8];
        pB[1][i] = (const char*)&Bs[rb][(4 * (1 - rb2) + cb2) * 8];
    }
    __syncthreads();

    float4v acc[2][2] = {};
    #pragma unroll
    for (int ksu = 0; ksu < 8; ++ksu) {
        short8 af[2], bfr[2];
        #pragma unroll
        for (int i = 0; i < 2; ++i) {
            af[i]  = *(const short8*)(pA[ksu & 1][i] + (ksu >> 1) * 128);
            bfr[i] = *(const short8*)(pB[ksu & 1][i] + (ksu >> 1) * 128);
        }
        #pragma unroll
        for (int i = 0; i < 2; ++i)
            #pragma unroll
            for (int j = 0; j < 2; ++j)
                acc[i][j] = __builtin_amdgcn_mfma_f32_16x16x32_bf16(af[i], bfr[j], acc[i][j], 0, 0, 0);
    }

    #pragma unroll
    for (int i = 0; i < 2; ++i)
        #pragma unroll
        for (int j = 0; j < 2; ++j) {
            const int rowb = wr * 32 + i * 16 + quad * 4;   // 4 consecutive rows
            const int col  = wc * 32 + j * 16 + lm;
            union { unsigned long long u; unsigned short s[4]; } pk;
            #pragma unroll
            for (int r = 0; r < 4; ++r) {
                float v = acc[i][j][r] * scale;
                long off = base + (long)(m0 + rowb + r) * 256 + n0 + col;
                if (CnBf) CnBf[off] = __float2bfloat16(v);
                if (CnF)  CnF[off]  = v;
                float tv = sgn * v + ((m0 + rowb + r) == (n0 + col) ? diag : 0.0f);
                pk.s[r] = bf16_bits(tv);
            }
            if (CTbf)
                *(unsigned long long*)&CTbf[base + (long)(n0 + col) * 256 + m0 + rowb] = pk.u;
        }
}

// ---------------------------------------------------------------------------
// Dual batched pinv GEMM: z' = 0.25 z @ t3 AND P' = 0.25 P @ t3 in one launch;
// P-half epilogue emits t1'^T = (7I - P')^T. 1024 blocks.
__launch_bounds__(256)
__global__ void gemm_pinv2(const __hip_bfloat16* __restrict__ zA,
                           const __hip_bfloat16* __restrict__ pAg,
                           const __hip_bfloat16* __restrict__ t3T,
                           __hip_bfloat16* __restrict__ zOut,
                           float* __restrict__ zF,
                           __hip_bfloat16* __restrict__ pOut,
                           __hip_bfloat16* __restrict__ t1T) {
    __shared__ __hip_bfloat16 As[64][256];
    __shared__ __hip_bfloat16 Bs[64][256];
    const int t = threadIdx.x;
    const int hw = blockIdx.y * 16 + blockIdx.x;     // grid (16, 64)
    const int lg = xcd_swz(hw, 1024);
    const int pair = lg >> 5;                        // batch 0..31
    const int half = (lg >> 4) & 1;                  // 0 = z, 1 = P
    const int tile = lg & 15;
    const long base = (long)pair << 16;
    const int m0 = (tile >> 2) * 64, n0 = (tile & 3) * 64;
    const int wave = t >> 6, lane = t & 63;
    const int wr = wave >> 1, wc = wave & 1;
    const int lm = lane & 15, quad = lane >> 4;
    const __hip_bfloat16* Ab = (half ? pAg : zA) + base;
    const __hip_bfloat16* Bb = t3T + base;

    #pragma unroll
    for (int p = 0; p < 8; ++p) {
        int idx = t + p * 256;
        int r = idx >> 5;
        int csrc = ((idx & 31) ^ (r & 7)) * 8;
        int cb = idx * 8;
        gl_lds16(&Ab[(long)(m0 + r) * 256 + csrc], &As[0][0] + cb);
        gl_lds16(&Bb[(long)(n0 + r) * 256 + csrc], &Bs[0][0] + cb);
    }

    const char* pA[2][2];
    const char* pB[2][2];
    #pragma unroll
    for (int i = 0; i < 2; ++i) {
        int ra = wr * 32 + i * 16 + lm;
        int rb = wc * 32 + i * 16 + lm;
        int ca = quad ^ (ra & 3), ra2 = (ra >> 2) & 1;
        int cb2 = quad ^ (rb & 3), rb2 = (rb >> 2) & 1;
        pA[0][i] = (const char*)&As[ra][(4 * ra2       + ca)  * 8];
        pA[1][i] = (const char*)&As[ra][(4 * (1 - ra2) + ca)  * 8];
        pB[0][i] = (const char*)&Bs[rb][(4 * rb2       + cb2) * 8];
        pB[1][i] = (const char*)&Bs[rb][(4 * (1 - rb2) + cb2) * 8];
    }
    __syncthreads();

    float4v acc[2][2] = {};
    #pragma unroll
    for (int ksu = 0; ksu < 8; ++ksu) {
        short8 af[2], bfr[2];
        #pragma unroll
        for (int i = 0; i < 2; ++i) {
            af[i]  = *(const short8*)(pA[ksu & 1][i] + (ksu >> 1) * 128);
            bfr[i] = *(const short8*)(pB[ksu & 1][i] + (ksu >> 1) * 128);
        }
        #pragma unroll
        for (int i = 0; i < 2; ++i)
            #pragma unroll
            for (int j = 0; j < 2; ++j)
                acc[i][j] = __builtin_amdgcn_mfma_f32_16x16x32_bf16(af[i], bfr[j], acc[i][j], 0, 0, 0);
    }

    #pragma unroll
    for (int i = 0; i < 2; ++i)
        #pragma unroll
        for (int j = 0; j < 2; ++j) {
            const int rowb = wr * 32 + i * 16 + quad * 4;
            const int col  = wc * 32 + j * 16 + lm;
            union { unsigned long long u; unsigned short s[4]; } pk;
            #pragma unroll
            for (int r = 0; r < 4; ++r) {
                float v = acc[i][j][r] * 0.25f;
                long off = base + (long)(m0 + rowb + r) * 256 + n0 + col;
                if (half == 0) {
                    zOut[off] = __float2bfloat16(v);
                    if (zF) zF[off] = v;
                } else {
                    pOut[off] = __float2bfloat16(v);
                    float tv = -v + ((m0 + rowb + r) == (n0 + col) ? 7.0f : 0.0f);
                    pk.s[r] = bf16_bits(tv);
                }
            }
            if (half)
                *(unsigned long long*)&t1T[base + (long)(n0 + col) * 256 + m0 + rowb] = pk.u;
        }
}

// ---------------------------------------------------------------------------
// pinv prep: a2_bf = bf16(a2); z0T = bf16(s*a2); z0n = bf16(s*a2^T). grid (4,4,32).
__launch_bounds__(256)
__global__ void pinv_prep(const float* __restrict__ a2, const float* __restrict__ scl,
                          __hip_bfloat16* __restrict__ a2bf, __hip_bfloat16* __restrict__ z0T,
                          __hip_bfloat16* __restrict__ z0n) {
    __shared__ float tl[64][65];
    const int t = threadIdx.x;
    const long base = (long)blockIdx.z << 16;
    const int i0 = blockIdx.y * 64, j0 = blockIdx.x * 64;
    float s = scl[0];
    #pragma unroll
    for (int p = 0; p < 16; ++p) {
        int idx = t + p * 256;
        int r = idx >> 6, c = idx & 63;
        long off = base + (long)(i0 + r) * 256 + j0 + c;
        float v = a2[off];
        a2bf[off] = __float2bfloat16(v);
        float zv = v * s;
        z0T[off] = __float2bfloat16(zv);
        tl[r][c] = zv;
    }
    __syncthreads();
    int r = t & 63;
    #pragma unroll
    for (int u = 0; u < 16; ++u) {
        int c = u * 4 + (t >> 6);
        z0n[base + (long)(j0 + c) * 256 + i0 + r] = __float2bfloat16(tl[r][c]);
    }
}

// ---------------------------------------------------------------------------
// Round-13: fused sim2 + row-softmax. Block = 64 rows x FULL 256 cols, K=64.
// grid 128 (= bh*4 tiles). acc layout: row = ty*4+r2, col = tx + 16*c
// (threads stride-1 in cols -> conflict-free LDS reads + coalesced writes).
// Row softmax via shfl_xor over the 16-thread tx group — no extra launch, no
// a2 round-trip.
__launch_bounds__(256)
__global__ void sim2_softmax(const float* __restrict__ q_l, const float* __restrict__ k_l,
                             float* __restrict__ a2) {
    const int t = threadIdx.x;
    const int lg = xcd_swz(blockIdx.x, 128);
    const int bh = lg >> 2;
    const int m0 = (lg & 3) * 64;
    const int tx = t & 15, ty = t >> 4;      // ty 0..15 -> 16 row-groups of 4
    const float* Ab = q_l + (long)bh * MM * DD;
    const float* Bb = k_l + (long)bh * MM * DD;

    __shared__ float As[16][64];
    __shared__ float Bs[16][256];

    float acc[4][16] = {};

    for (int k0 = 0; k0 < DD; k0 += 16) {
        {   // stage A: 64 rows x 16 k
            int r = t >> 2, kk4 = (t & 3) * 4;
            float4 va = *(const float4*)(Ab + (long)(m0 + r) * DD + k0 + kk4);
            As[kk4 + 0][r] = va.x; As[kk4 + 1][r] = va.y; As[kk4 + 2][r] = va.z; As[kk4 + 3][r] = va.w;
        }
        {   // stage B^T: col j = t, 16 k values
            #pragma unroll
            for (int g = 0; g < 4; ++g) {
                float4 vb = *(const float4*)(Bb + (long)t * DD + k0 + g * 4);
                Bs[g * 4 + 0][t] = vb.x; Bs[g * 4 + 1][t] = vb.y;
                Bs[g * 4 + 2][t] = vb.z; Bs[g * 4 + 3][t] = vb.w;
            }
        }
        __syncthreads();
        #pragma unroll
        for (int kk = 0; kk < 16; ++kk) {
            float a[4], b[16];
            #pragma unroll
            for (int r2 = 0; r2 < 4; ++r2) a[r2] = As[kk][ty * 4 + r2];
            #pragma unroll
            for (int c = 0; c < 16; ++c) b[c] = Bs[kk][tx + 16 * c];
            #pragma unroll
            for (int r2 = 0; r2 < 4; ++r2)
                #pragma unroll
                for (int c = 0; c < 16; ++c)
                    acc[r2][c] += a[r2] * b[c];
        }
        __syncthreads();
    }

    // row softmax: reduce over 16 local cols + 16-lane tx group
    float* outb = a2 + ((long)bh << 16);
    #pragma unroll
    for (int r2 = 0; r2 < 4; ++r2) {
        float mx = acc[r2][0];
        #pragma unroll
        for (int c = 1; c < 16; ++c) mx = fmaxf(mx, acc[r2][c]);
        mx = fmaxf(mx, __shfl_xor(mx, 1));
        mx = fmaxf(mx, __shfl_xor(mx, 2));
        mx = fmaxf(mx, __shfl_xor(mx, 4));
        mx = fmaxf(mx, __shfl_xor(mx, 8));
        float sum = 0.f;
        #pragma unroll
        for (int c = 0; c < 16; ++c) {
            acc[r2][c] = __expf(acc[r2][c] - mx);
            sum += acc[r2][c];
        }
        sum += __shfl_xor(sum, 1);
        sum += __shfl_xor(sum, 2);
        sum += __shfl_xor(sum, 4);
        sum += __shfl_xor(sum, 8);
        float inv = 1.0f / sum;
        int row = m0 + ty * 4 + r2;
        #pragma unroll
        for (int c = 0; c < 16; ++c)
            outb[(long)row * 256 + tx + 16 * c] = acc[r2][c] * inv;
    }
}

// ---------------------------------------------------------------------------
// Generic fp32 tiled GEMM. 64x64 tile, BK=16. XCD-chunk swizzled.
// Round-13: optional transposed bf16 output (wtT != nullptr) — writes
// wtT[bz][col][row] directly, skipping the separate transpose kernel.
__launch_bounds__(256)
__global__ void gemm64(const float* __restrict__ A, const float* __restrict__ Bm,
                       float* __restrict__ C, __hip_bfloat16* __restrict__ wtT,
                       int M, int N, int K, long sA, long sB, long sC, float alpha) {
    const int gx = gridDim.x, gxy = gridDim.x * gridDim.y;
    const int hw = blockIdx.z * gxy + blockIdx.y * gx + blockIdx.x;
    const int lg = xcd_swz(hw, gxy * gridDim.z);
    const int bz = lg / gxy;
    const int rem = lg % gxy;
    const float* Ab = A + (long)bz * sA;
    const float* Bb = Bm + (long)bz * sB;

    __shared__ float As[16][64];
    __shared__ float Bs[16][64];

    const int tid = threadIdx.x;
    const int tx = tid & 15;
    const int ty = tid >> 4;
    const int m0 = (rem / gx) * 64;
    const int n0 = (rem % gx) * 64;

    float acc[4][4] = {};

    for (int k0 = 0; k0 < K; k0 += 16) {
        {
            int r  = tid >> 2;
            int kk = (tid & 3) * 4;
            float4 va = *(const float4*)(Ab + (long)(m0 + r) * K + k0 + kk);
            As[kk + 0][r] = va.x; As[kk + 1][r] = va.y; As[kk + 2][r] = va.z; As[kk + 3][r] = va.w;
        }
        {
            int kk = tid >> 4;
            int j  = (tid & 15) * 4;
            float4 vb = *(const float4*)(Bb + (long)(k0 + kk) * N + n0 + j);
            Bs[kk][j + 0] = vb.x; Bs[kk][j + 1] = vb.y; Bs[kk][j + 2] = vb.z; Bs[kk][j + 3] = vb.w;
        }
        __syncthreads();
        #pragma unroll
        for (int kk = 0; kk < 16; ++kk) {
            float a0 = As[kk][ty * 4 + 0], a1 = As[kk][ty * 4 + 1];
            float a2 = As[kk][ty * 4 + 2], a3 = As[kk][ty * 4 + 3];
            float b0 = Bs[kk][tx * 4 + 0], b1 = Bs[kk][tx * 4 + 1];
            float b2 = Bs[kk][tx * 4 + 2], b3 = Bs[kk][tx * 4 + 3];
            acc[0][0] += a0 * b0; acc[0][1] += a0 * b1; acc[0][2] += a0 * b2; acc[0][3] += a0 * b3;
            acc[1][0] += a1 * b0; acc[1][1] += a1 * b1; acc[1][2] += a1 * b2; acc[1][3] += a1 * b3;
            acc[2][0] += a2 * b0; acc[2][1] += a2 * b1; acc[2][2] += a2 * b2; acc[2][3] += a2 * b3;
            acc[3][0] += a3 * b0; acc[3][1] += a3 * b1; acc[3][2] += a3 * b2; acc[3][3] += a3 * b3;
        }
        __syncthreads();
    }

    if (wtT) {
        __hip_bfloat16* wb = wtT + (long)bz * DD * MM;
        #pragma unroll
        for (int r = 0; r < 4; ++r)
            #pragma unroll
            for (int c = 0; c < 4; ++c)
                wb[(long)(n0 + tx * 4 + c) * MM + m0 + ty * 4 + r] = __float2bfloat16(acc[r][c] * alpha);
    } else {
        float* Cb = C + (long)bz * sC;
        #pragma unroll
        for (int r = 0; r < 4; ++r)
            #pragma unroll
            for (int c = 0; c < 4; ++c)
                Cb[(long)(m0 + ty * 4 + r) * N + n0 + tx * 4 + c] = acc[r][c] * alpha;
    }
}

// ---------------------------------------------------------------------------
// Landmark means from bf16 q/k; writes fp32 (for sim2) and bf16 (for MFMA flash).
__global__ void landmark_kernel(const __hip_bfloat16* __restrict__ qb,
                                const __hip_bfloat16* __restrict__ kb,
                                float* __restrict__ q_l, float* __restrict__ k_l,
                                __hip_bfloat16* __restrict__ q_lb,
                                __hip_bfloat16* __restrict__ k_lb) {
    int bh = blockIdx.x >> 8;
    int m  = blockIdx.x & 255;
    int d  = threadIdx.x;     // 64
    const __hip_bfloat16* src = (blockIdx.y ? kb : qb) + ((long)bh * NN + m * LL) * DD + d;
    float s = 0.f;
    #pragma unroll
    for (int t = 0; t < LL; ++t) s += __bfloat162float(src[(long)t * DD]);
    s *= (1.0f / LL);
    long off = ((long)bh * MM + m) * DD + d;
    if (blockIdx.y) { k_l[off] = s; k_lb[off] = __float2bfloat16(s); }
    else            { q_l[off] = s; q_lb[off] = __float2bfloat16(s); }
}

// ---------------------------------------------------------------------------
// Max column-sum of a2 (row-sums are 1.0: softmax rows). 256 blocks.
__launch_bounds__(256)
__global__ void redmax_kernel(const float* __restrict__ a2, float* __restrict__ red) {
    int blk = blockIdx.x;            // bh*8 + cg
    int bh = blk >> 3, cg = blk & 7;
    int t = threadIdx.x;
    const float* Ab = a2 + ((long)bh << 16) + cg * 32;
    int c = t & 31, rg = t >> 5;     // col 0..31, row-group 0..7
    float s = 0.f;
    for (int r = rg * 32; r < rg * 32 + 32; ++r) s += Ab[(long)r * 256 + c];
    __shared__ float m[256];
    m[t] = s;
    __syncthreads();
    if (t < 32) {
        float cs = 0.f;
        #pragma unroll
        for (int g = 0; g < 8; ++g) cs += m[t + 32 * g];
        m[t] = cs;
    }
    __syncthreads();
    if (t == 0) {
        float mx = m[0];
        #pragma unroll
        for (int i = 1; i < 32; ++i) mx = fmaxf(mx, m[i]);
        red[blk] = mx;
    }
}

__launch_bounds__(256)
__global__ void scale_kernel(const float* __restrict__ red, float* __restrict__ scl) {
    __shared__ float b[256];
    int t = threadIdx.x;  // 256
    b[t] = red[t];
    __syncthreads();
    for (int off = 128; off > 0; off >>= 1) {
        if (t < off) b[t] = fmaxf(b[t], b[t + off]);
        __syncthreads();
    }
    if (t == 0) scl[0] = 1.0f / b[0];
}

// ---------------------------------------------------------------------------
// a3v flash MFMA: block = 64 landmark rows x 1024-seq slice (16 chunks of 64).
// K/V register prefetch one chunk ahead + lgkm-only barriers. XCD-swizzled.
__launch_bounds__(256)
__global__ void a3v_mfma(const __hip_bfloat16* __restrict__ qlb,
                         const __hip_bfloat16* __restrict__ kb,
                         const __hip_bfloat16* __restrict__ vtb,
                         float* __restrict__ opart, float* __restrict__ lpart) {
    const int hw = blockIdx.y * 16 + blockIdx.x;
    const int lg = xcd_swz(hw, 512);
    const int bh = lg >> 4;
    const int mt = (lg >> 2) & 3;
    const int ns = lg & 3;
    const int t = threadIdx.x;
    const int wave = t >> 6, lane = t & 63;
    const int wr = wave >> 1, wc = wave & 1;
    const int lm = lane & 15, quad = lane >> 4;
    const int r8 = t >> 3, c8 = (t & 7) * 8;

    __shared__ __hip_bfloat16 Qs[64][72];
    __shared__ __hip_bfloat16 Ks[64][72];
    __shared__ __hip_bfloat16 Vt[64][72];
    __shared__ __hip_bfloat16 Ps[64][72];
    __shared__ float lredS[64][2];

    {
        const __hip_bfloat16* qbase = qlb + ((long)bh * MM + mt * 64) * DD;
        *(uint4*)&Qs[r8][c8]      = *(const uint4*)&qbase[(long)r8 * DD + c8];
        *(uint4*)&Qs[r8 + 32][c8] = *(const uint4*)&qbase[(long)(r8 + 32) * DD + c8];
    }

    float4v acc[2][2] = {};
    float lacc[2][4] = {};
    const __hip_bfloat16* kbase = kb + ((long)bh * NN + ns * 1024) * DD;
    const __hip_bfloat16* vbase = vtb + (long)bh * DD * NN + ns * 1024;

    // prefetch chunk 0 into regs
    uint4 kv0 = *(const uint4*)&kbase[(long)r8 * DD + c8];
    uint4 kv1 = *(const uint4*)&kbase[(long)(r8 + 32) * DD + c8];
    uint4 vv0 = *(const uint4*)&vbase[(long)r8 * NN + c8];
    uint4 vv1 = *(const uint4*)&vbase[(long)(r8 + 32) * NN + c8];
    bar_nv();   // Qs visible; prefetch stays in flight

    for (int ch = 0; ch < 16; ++ch) {
        *(uint4*)&Ks[r8][c8]      = kv0;
        *(uint4*)&Ks[r8 + 32][c8] = kv1;
        *(uint4*)&Vt[r8][c8]      = vv0;
        *(uint4*)&Vt[r8 + 32][c8] = vv1;
        if (ch < 15) {   // issue next chunk's loads; they fly during compute
            kv0 = *(const uint4*)&kbase[(long)((ch + 1) * 64 + r8) * DD + c8];
            kv1 = *(const uint4*)&kbase[(long)((ch + 1) * 64 + r8 + 32) * DD + c8];
            vv0 = *(const uint4*)&vbase[(long)r8 * NN + (ch + 1) * 64 + c8];
            vv1 = *(const uint4*)&vbase[(long)(r8 + 32) * NN + (ch + 1) * 64 + c8];
        }
        bar_nv();

        float4v s[2][2] = {};
        #pragma unroll
        for (int ks = 0; ks < 64; ks += 32) {
            short8 af[2], bfr[2];
            #pragma unroll
            for (int i = 0; i < 2; ++i) {
                af[i]  = *(const short8*)&Qs[wr * 32 + i * 16 + lm][ks + quad * 8];
                bfr[i] = *(const short8*)&Ks[wc * 32 + i * 16 + lm][ks + quad * 8];
            }
            #pragma unroll
            for (int i = 0; i < 2; ++i)
                #pragma unroll
                for (int j = 0; j < 2; ++j)
                    s[i][j] = __builtin_amdgcn_mfma_f32_16x16x32_bf16(af[i], bfr[j], s[i][j], 0, 0, 0);
        }
        #pragma unroll
        for (int i = 0; i < 2; ++i)
            #pragma unroll
            for (int j = 0; j < 2; ++j)
                #pragma unroll
                for (int r2 = 0; r2 < 4; ++r2) {
                    float e = __expf(s[i][j][r2]);
                    lacc[i][r2] += e;
                    Ps[wr * 32 + i * 16 + quad * 4 + r2][wc * 32 + j * 16 + lm] = __float2bfloat16(e);
                }
        bar_nv();

        #pragma unroll
        for (int ks = 0; ks < 64; ks += 32) {
            short8 af[2], bfr[2];
            #pragma unroll
            for (int i = 0; i < 2; ++i) {
                af[i]  = *(const short8*)&Ps[wr * 32 + i * 16 + lm][ks + quad * 8];
                bfr[i] = *(const short8*)&Vt[wc * 32 + i * 16 + lm][ks + quad * 8];
            }
            #pragma unroll
            for (int i = 0; i < 2; ++i)
                #pragma unroll
                for (int j = 0; j < 2; ++j)
                    acc[i][j] = __builtin_amdgcn_mfma_f32_16x16x32_bf16(af[i], bfr[j], acc[i][j], 0, 0, 0);
        }
        bar_nv();
    }

    // wave-level l-sum reduction over the 16 lm lanes
    #pragma unroll
    for (int i = 0; i < 2; ++i)
        #pragma unroll
        for (int r2 = 0; r2 < 4; ++r2) {
            float s = lacc[i][r2];
            s += __shfl_xor(s, 1);
            s += __shfl_xor(s, 2);
            s += __shfl_xor(s, 4);
            s += __shfl_xor(s, 8);
            if (lm == 0) lredS[wr * 32 + i * 16 + quad * 4 + r2][wc] = s;
        }
    __syncthreads();
    if (t < 64)
        lpart[((bh * 4 + mt) * 4 + ns) * 64 + t] = lredS[t][0] + lredS[t][1];
    const long pbase = ((long)((bh * 4 + mt) * 4 + ns)) << 12;
    #pragma unroll
    for (int i = 0; i < 2; ++i)
        #pragma unroll
        for (int j = 0; j < 2; ++j)
            #pragma unroll
            for (int r2 = 0; r2 < 4; ++r2)
                opart[pbase + (long)(wr * 32 + i * 16 + quad * 4 + r2) * 64 + wc * 32 + j * 16 + lm] = acc[i][j][r2];
}

// stage 2: combine 4 n-split partials
__global__ void a3v_combine(const float* __restrict__ opart, const float* __restrict__ lpart,
                            float* __restrict__ a3v) {
    int idx = blockIdx.x * 256 + threadIdx.x;
    int d  = idx & 63;
    int m  = (idx >> 6) & 255;
    int bh = idx >> 14;
    int mt = m >> 6, r = m & 63;
    int pb = (bh * 4 + mt) * 4;
    float osum = 0.f, lsum = 0.f;
    #pragma unroll
    for (int ns = 0; ns < 4; ++ns) {
        osum += opart[(((long)(pb + ns)) << 12) + r * 64 + d];
        lsum += lpart[(pb + ns) * 64 + r];
    }
    a3v[((long)bh * MM + m) * DD + d] = osum / lsum;
}

// ---------------------------------------------------------------------------
// attn_out flash MFMA + Toeplitz-MFMA depthwise conv. XCD-swizzled.
__launch_bounds__(256)
__global__ void attn_out_mfma(const __hip_bfloat16* __restrict__ qb,
                              const __hip_bfloat16* __restrict__ klb,
                              const __hip_bfloat16* __restrict__ wtb,
                              const __hip_bfloat16* __restrict__ vtb,
                              const float* __restrict__ convw,
                              __hip_bfloat16* __restrict__ ctx) {
    const int hw = blockIdx.y * 64 + blockIdx.x;
    const int lg = xcd_swz(hw, 2048);
    const int bh = lg >> 6;
    const int b = bh >> 3, h = bh & 7;
    const int i0 = (lg & 63) * 64;
    const int t = threadIdx.x;
    const int wave = t >> 6, lane = t & 63;
    const int wr = wave >> 1, wc = wave & 1;
    const int lm = lane & 15, quad = lane >> 4;
    const int r8 = t >> 3, c8 = (t & 7) * 8;

    __shared__ __hip_bfloat16 Qs[64][72];
    __shared__ __hip_bfloat16 KW[2][64][72];   // Ks = KW[0], Wt = KW[1]; Tpl aliases
    __shared__ __hip_bfloat16 Ps[64][72];
    __shared__ __hip_bfloat16 Vc[64][104];     // v window [i0-16, i0+80): cols 0..95
    __shared__ float lredS[64][2];
    __shared__ float dsum[64];
    __shared__ float cwS[KS];
    __hip_bfloat16 (*Tpl)[104] = reinterpret_cast<__hip_bfloat16 (*)[104]>(&KW[0][0][0]);

    if (t < KS) cwS[t] = convw[h * KS + t];

    {   // stage Q tile
        const __hip_bfloat16* qbase = qb + ((long)bh * NN + i0) * DD;
        *(uint4*)&Qs[r8][c8]      = *(const uint4*)&qbase[(long)r8 * DD + c8];
        *(uint4*)&Qs[r8 + 32][c8] = *(const uint4*)&qbase[(long)(r8 + 32) * DD + c8];
    }
    {   // stage V conv window: 64 dd x 12 chunks of 8 bf16
        for (int c = t; c < 768; c += 256) {
            int dd = c / 12, u = c - dd * 12;
            int g0 = i0 - 16 + u * 8;
            const __hip_bfloat16* vrow = vtb + ((long)bh * DD + dd) * NN;
            __align__(16) __hip_bfloat16 tmp[8];
            if (g0 >= 0 && g0 + 8 <= NN) {
                *(uint4*)tmp = *(const uint4*)&vrow[g0];
            } else {
                #pragma unroll
                for (int e = 0; e < 8; ++e) {
                    int g = g0 + e;
                    tmp[e] = (g >= 0 && g < NN) ? vrow[g] : __float2bfloat16(0.f);
                }
            }
            *(uint4*)&Vc[dd][u * 8] = *(uint4*)tmp;
        }
    }
    __syncthreads();   // cwS, Qs, Vc visible

    {   // build Toeplitz matrix in the Ks/Wt space: T[r][c] = w[c-r], 0 <= c-r < 33
        int r  = t >> 2;            // 0..63
        int c0 = (t & 3) * 24;      // 4 col-groups of 24
        #pragma unroll
        for (int u = 0; u < 12; ++u) {
            int c = c0 + u * 2;
            int d0 = c - r, d1 = c + 1 - r;
            unsigned short lo = (d0 >= 0 && d0 < KS) ? bf16_bits(cwS[d0]) : (unsigned short)0;
            unsigned short hi = (d1 >= 0 && d1 < KS) ? bf16_bits(cwS[d1]) : (unsigned short)0;
            *(unsigned*)&Tpl[r][c] = ((unsigned)hi << 16) | lo;
        }
    }
    bar_nv();          // Tpl visible

    // prefetch chunk 0's K/W into regs: latency hides under the conv MFMAs
    const __hip_bfloat16* klbase = klb + (long)bh * MM * DD;
    const __hip_bfloat16* wbase  = wtb + (long)bh * DD * MM;
    uint4 kv0 = *(const uint4*)&klbase[(long)r8 * DD + c8];
    uint4 kv1 = *(const uint4*)&klbase[(long)(r8 + 32) * DD + c8];
    uint4 wv0 = *(const uint4*)&wbase[(long)r8 * MM + c8];
    uint4 wv1 = *(const uint4*)&wbase[(long)(r8 + 32) * MM + c8];

    // conv via Toeplitz MFMA: accC[row][dd] = sum_s T[row][s] * Vc[dd][s]
    float4v accC[2][2] = {};
    #pragma unroll
    for (int ks = 0; ks < 96; ks += 32) {
        short8 af[2], bfr[2];
        #pragma unroll
        for (int i = 0; i < 2; ++i) {
            af[i]  = *(const short8*)&Tpl[wr * 32 + i * 16 + lm][ks + quad * 8];
            bfr[i] = *(const short8*)&Vc[wc * 32 + i * 16 + lm][ks + quad * 8];
        }
        #pragma unroll
        for (int i = 0; i < 2; ++i)
            #pragma unroll
            for (int j = 0; j < 2; ++j)
                accC[i][j] = __builtin_amdgcn_mfma_f32_16x16x32_bf16(af[i], bfr[j], accC[i][j], 0, 0, 0);
    }
    bar_nv();          // conv reads done; KW space free for K/W staging

    float4v acc[2][2] = {};
    float lacc[2][4] = {};

    for (int ch = 0; ch < 4; ++ch) {
        *(uint4*)&KW[0][r8][c8]      = kv0;
        *(uint4*)&KW[0][r8 + 32][c8] = kv1;
        *(uint4*)&KW[1][r8][c8]      = wv0;
        *(uint4*)&KW[1][r8 + 32][c8] = wv1;
        if (ch < 3) {   // next chunk's loads fly during this chunk's compute
            kv0 = *(const uint4*)&klbase[(long)((ch + 1) * 64 + r8) * DD + c8];
            kv1 = *(const uint4*)&klbase[(long)((ch + 1) * 64 + r8 + 32) * DD + c8];
            wv0 = *(const uint4*)&wbase[(long)r8 * MM + (ch + 1) * 64 + c8];
            wv1 = *(const uint4*)&wbase[(long)(r8 + 32) * MM + (ch + 1) * 64 + c8];
        }
        bar_nv();

        float4v s[2][2] = {};
        #pragma unroll
        for (int ks = 0; ks < 64; ks += 32) {
            short8 af[2], bfr[2];
            #pragma unroll
            for (int i = 0; i < 2; ++i) {
                af[i]  = *(const short8*)&Qs[wr * 32 + i * 16 + lm][ks + quad * 8];
                bfr[i] = *(const short8*)&KW[0][wc * 32 + i * 16 + lm][ks + quad * 8];
            }
            #pragma unroll
            for (int i = 0; i < 2; ++i)
                #pragma unroll
                for (int j = 0; j < 2; ++j)
                    s[i][j] = __builtin_amdgcn_mfma_f32_16x16x32_bf16(af[i], bfr[j], s[i][j], 0, 0, 0);
        }
        #pragma unroll
        for (int i = 0; i < 2; ++i)
            #pragma unroll
            for (int j = 0; j < 2; ++j)
                #pragma unroll
                for (int r2 = 0; r2 < 4; ++r2) {
                    float e = __expf(s[i][j][r2]);
                    lacc[i][r2] += e;
                    Ps[wr * 32 + i * 16 + quad * 4 + r2][wc * 32 + j * 16 + lm] = __float2bfloat16(e);
                }
        bar_nv();

        #pragma unroll
        for (int ks = 0; ks < 64; ks += 32) {
            short8 af[2], bfr[2];
            #pragma unroll
            for (int i = 0; i < 2; ++i) {
                af[i]  = *(const short8*)&Ps[wr * 32 + i * 16 + lm][ks + quad * 8];
                bfr[i] = *(const short8*)&KW[1][wc * 32 + i * 16 + lm][ks + quad * 8];
            }
            #pragma unroll
            for (int i = 0; i < 2; ++i)
                #pragma unroll
                for (int j = 0; j < 2; ++j)
                    acc[i][j] = __builtin_amdgcn_mfma_f32_16x16x32_bf16(af[i], bfr[j], acc[i][j], 0, 0, 0);
        }
        bar_nv();
    }

    // wave-level l-sum reduction over the 16 lm lanes
    #pragma unroll
    for (int i = 0; i < 2; ++i)
        #pragma unroll
        for (int r2 = 0; r2 < 4; ++r2) {
            float s = lacc[i][r2];
            s += __shfl_xor(s, 1);
            s += __shfl_xor(s, 2);
            s += __shfl_xor(s, 4);
            s += __shfl_xor(s, 8);
            if (lm == 0) lredS[wr * 32 + i * 16 + quad * 4 + r2][wc] = s;
        }
    __syncthreads();
    if (t < 64) dsum[t] = 1.0f / (lredS[t][0] + lredS[t][1]);
    __syncthreads();

    // epilogue: normalize + add conv + single ctx write
    #pragma unroll
    for (int j = 0; j < 2; ++j) {
        int dd = wc * 32 + j * 16 + lm;
        #pragma unroll
        for (int i = 0; i < 2; ++i) {
            int R = wr * 32 + i * 16 + quad * 4;
            #pragma unroll
            for (int r2 = 0; r2 < 4; ++r2) {
                int row = R + r2;
                ctx[((long)b * NN + i0 + row) * DIMM + h * DD + dd] =
                    __float2bfloat16(acc[i][j][r2] * dsum[row] + accC[i][j][r2]);
            }
        }
    }
}

// ---------------------------------------------------------------------------
extern "C" void kernel_launch(void* const* d_in, const int* in_sizes, int n_in,
                              void* d_out, int out_size, void* d_ws, size_t ws_size,
                              hipStream_t stream) {
    const float* x      = (const float*)d_in[0];
    const float* norm_w = (const float*)d_in[1];
    const float* norm_b = (const float*)d_in[2];
    const float* Wqkv   = (const float*)d_in[3];
    const float* Wout   = (const float*)d_in[4];
    const float* bout   = (const float*)d_in[5];
    const float* conv_w = (const float*)d_in[6];
    float* out = (float*)d_out;

    float* ws = (float*)d_ws;
    size_t o = 0;
    auto alloc = [&](size_t n) { float* p = ws + o; o += n; return p; };
    auto allocb = [&](size_t n) { return (__hip_bfloat16*)alloc((n + 1) / 2); };

    __hip_bfloat16* xn_bf  = allocb((size_t)NROW * DIMM);
    __hip_bfloat16* wqt_bf = allocb((size_t)3 * DIMM * DIMM);
    __hip_bfloat16* wot_bf = allocb((size_t)DIMM * DIMM);
    __hip_bfloat16* ctx_bf = allocb((size_t)NROW * DIMM);
    __hip_bfloat16* q_bf   = allocb((size_t)BHH * NN * DD);
    __hip_bfloat16* k_bf   = allocb((size_t)BHH * NN * DD);
    __hip_bfloat16* vt_bf  = allocb((size_t)BHH * DD * NN);
    __hip_bfloat16* qlb    = allocb((size_t)BHH * MM * DD);
    __hip_bfloat16* klb    = allocb((size_t)BHH * MM * DD);
    __hip_bfloat16* wt_bf  = allocb((size_t)BHH * DD * MM);
    float* q_l  = alloc((size_t)BHH * MM * DD);
    float* k_l  = alloc((size_t)BHH * MM * DD);
    float* a2   = alloc((size_t)BHH * MM * MM);
    float* zb   = alloc((size_t)BHH * MM * MM);
    float* az   = alloc((size_t)BHH * MM * MM);
    float* gb   = alloc((size_t)BHH * MM * MM);
    float* tb   = alloc((size_t)BHH * MM * MM);
    float* z2   = alloc((size_t)BHH * MM * MM);
    float* a3v  = alloc((size_t)BHH * MM * DD);
    float* opart = alloc((size_t)BHH * 4 * 4 * 64 * 64);
    float* lpart = alloc((size_t)BHH * 4 * 4 * 64);
    float* red  = alloc(256);
    float* scl  = alloc(64);

    // bf16 pinv slots (each 2M bf16 = one half of a 4MB fp32 buffer):
    const size_t HB = 1048576;
    __hip_bfloat16* a2bf = (__hip_bfloat16*)az;          // s0
    __hip_bfloat16* z0Tb = (__hip_bfloat16*)(az + HB);   // s1
    __hip_bfloat16* zpA  = (__hip_bfloat16*)gb;          // s2
    __hip_bfloat16* zpB  = (__hip_bfloat16*)(gb + HB);   // s3
    __hip_bfloat16* PnA  = (__hip_bfloat16*)tb;          // s4
    __hip_bfloat16* t1A  = (__hip_bfloat16*)(tb + HB);   // s5
    __hip_bfloat16* t2T  = (__hip_bfloat16*)z2;          // s6
    __hip_bfloat16* t3Tb = (__hip_bfloat16*)(z2 + HB);   // s7

    // 1. LayerNorm -> bf16
    ln_kernel<<<NROW, 256, 0, stream>>>(x, norm_w, norm_b, xn_bf);

    // 1b. transpose+convert weights
    transpose_bf16<<<dim3(3 * DIMM / 32, DIMM / 32), 256, 0, stream>>>(Wqkv, wqt_bf, DIMM, 3 * DIMM);
    transpose_bf16<<<dim3(DIMM / 32, DIMM / 32), 256, 0, stream>>>(Wout, wot_bf, DIMM, DIMM);

    // 2. QKV GEMM (MFMA): q,k bf16 natural; v transposed bf16
    gemm_mfma<EPI_QKV><<<dim3(3 * DIMM / 128, NROW / 128), 256, 0, stream>>>(
        xn_bf, wqt_bf, nullptr, NROW, 3 * DIMM, DIMM,
        nullptr, nullptr, q_bf, k_bf, vt_bf);

    // 3. Landmarks (fp32 + bf16)
    landmark_kernel<<<dim3(BHH * MM, 2), 64, 0, stream>>>(q_bf, k_bf, q_l, k_l, qlb, klb);

    // 4-5. sim2 + row softmax fused -> a2 (full-row tiles, in-register softmax)
    sim2_softmax<<<128, 256, 0, stream>>>(q_l, k_l, a2);

    // 6-7. pinv normalization scalar (max col-sum; row-sums are 1)
    redmax_kernel<<<BHH * 8, 256, 0, stream>>>(a2, red);
    scale_kernel<<<1, 256, 0, stream>>>(red, scl);

    // 8. pinv prep: a2bf, z0T (=s*a2, Bt of P0), z0n (=s*a2^T, z ping-A)
    dim3 g512(4, 4, BHH);
    pinv_prep<<<g512, 256, 0, stream>>>(a2, scl, a2bf, z0Tb, zpA);

    // 9. Newton-Schulz with az-recurrence (19 launches)
    gemm_pinv<<<g512, 256, 0, stream>>>(a2bf, z0Tb, PnA, nullptr, t1A, 7.0f, -1.0f, 1.0f);
    __hip_bfloat16 *zi = zpA, *zo = zpB;
    __hip_bfloat16 *Pc = PnA, *Pn2 = a2bf;    // a2bf slot free after P0
    __hip_bfloat16 *t1c = t1A, *t1n = z0Tb;   // z0T slot free after P0
    for (int it = 0; it < 6; ++it) {
        gemm_pinv<<<g512, 256, 0, stream>>>(Pc, t1c, nullptr, nullptr, t2T, 15.0f, -1.0f, 1.0f);
        gemm_pinv<<<g512, 256, 0, stream>>>(Pc, t2T, nullptr, nullptr, t3Tb, 13.0f, -1.0f, 1.0f);
        gemm_pinv2<<<dim3(16, 64), 256, 0, stream>>>(zi, Pc, t3Tb, zo,
                                                     (it == 5) ? zb : nullptr, Pn2, t1n);
        __hip_bfloat16* tmp;
        tmp = zi; zi = zo; zo = tmp;
        tmp = Pc; Pc = Pn2; Pn2 = tmp;
        tmp = t1c; t1c = t1n; t1n = tmp;
    }
    // zb = a2_inv (fp32)

    // 10. a3v = softmax(q_l . k^T) @ v   (MFMA flash)
    a3v_mfma<<<dim3(16, BHH), 256, 0, stream>>>(qlb, k_bf, vt_bf, opart, lpart);
    a3v_combine<<<BHH * MM * DD / 256, 256, 0, stream>>>(opart, lpart, a3v);

    // 11. wm = a2_inv @ a3v with fused transposed-bf16 output -> wt_bf
    gemm64<<<dim3(1, 4, BHH), 256, 0, stream>>>(
        zb, a3v, nullptr, wt_bf, MM, DD, MM, (long)MM * MM, (long)MM * DD, (long)MM * DD, 1.0f);

    // 12. attention out + fused depthwise conv -> bf16 ctx
    attn_out_mfma<<<dim3(NN / 64, BHH), 256, 0, stream>>>(
        q_bf, klb, wt_bf, vt_bf, conv_w, ctx_bf);

    // 13. final: out = x + ctx @ Wout + bout  (MFMA)
    gemm_mfma<EPI_OUT><<<dim3(DIMM / 128, NROW / 128), 256, 0, stream>>>(
        ctx_bf, wot_bf, out, NROW, DIMM, DIMM,
        bout, x, nullptr, nullptr, nullptr);
}